// Round 1
// baseline (1164.804 us; speedup 1.0000x reference)
//
#include <hip/hip_runtime.h>
#include <math.h>

// Pipeline:
//   ws layout: deg_out[N] | deg_in[N] | norm[N] | row_off[N+1(+pad)] | fill[N] |
//              col[E] | hx[N*128] | h[N*128]   (~110.8 MB)
//   1. memset deg_out/deg_in
//   2. k_deg     : atomic degree histograms (out-deg by src, in-deg by dst)
//   3. k_norm    : norm = 1/max(deg_out,1)
//   4. k_scan    : exclusive prefix of deg_in -> row_off, fill  (1 block)
//   5. k_fill    : CSR column fill (src sorted by dst via atomic slot counters)
//   6. k_gemm<256>: hx = (feat @ W_shared) * norm[row]
//   7. k_spmm_relu: h[n] = relu(sum_{e in CSR[n]} hx[col[e]] + b_shared)
//   8. k_gemm<128>: hc = (h @ [W_mu | W_ls]) * norm[row]   (into hx buffer)
//   9. k_spmm_out : acc = sum hc rows; out = (acc_mu+b_mu) + noise*exp(acc_ls+b_ls)

__global__ __launch_bounds__(256)
void k_deg(const int* __restrict__ src, const int* __restrict__ dst,
           int* __restrict__ deg_out, int* __restrict__ deg_in, int E) {
    int e = blockIdx.x * blockDim.x + threadIdx.x;
    if (e < E) {
        atomicAdd(&deg_out[src[e]], 1);
        atomicAdd(&deg_in[dst[e]], 1);
    }
}

__global__ __launch_bounds__(256)
void k_norm(const int* __restrict__ deg_out, float* __restrict__ norm, int N) {
    int n = blockIdx.x * blockDim.x + threadIdx.x;
    if (n < N) {
        int d = deg_out[n];
        norm[n] = 1.0f / (float)(d > 1 ? d : 1);
    }
}

// Single-block exclusive scan of deg_in -> row_off (and a copy into fill).
__global__ __launch_bounds__(1024)
void k_scan(const int* __restrict__ deg_in, int* __restrict__ row_off,
            int* __restrict__ fill, int N) {
    __shared__ int sums[1024];
    int tid = threadIdx.x;
    int chunk = (N + 1023) >> 10;
    int base = tid * chunk;
    int s = 0;
    for (int i = 0; i < chunk; ++i) {
        int idx = base + i;
        if (idx < N) s += deg_in[idx];
    }
    sums[tid] = s;
    __syncthreads();
    // Hillis-Steele inclusive scan over the 1024 partials
    for (int off = 1; off < 1024; off <<= 1) {
        int v = (tid >= off) ? sums[tid - off] : 0;
        __syncthreads();
        sums[tid] += v;
        __syncthreads();
    }
    int excl = (tid == 0) ? 0 : sums[tid - 1];
    for (int i = 0; i < chunk; ++i) {
        int idx = base + i;
        if (idx < N) {
            row_off[idx] = excl;
            fill[idx] = excl;
            excl += deg_in[idx];
        }
    }
    if (tid == 0) row_off[N] = sums[1023];
}

__global__ __launch_bounds__(256)
void k_fill(const int* __restrict__ src, const int* __restrict__ dst,
            int* __restrict__ fill, int* __restrict__ col, int E) {
    int e = blockIdx.x * blockDim.x + threadIdx.x;
    if (e < E) {
        int p = atomicAdd(&fill[dst[e]], 1);
        col[p] = src[e];
    }
}

// FP32 GEMM: out[M,128] = (A[M,K] @ W[K,128]) * norm[row]
// W given as two [K,64] halves (Wa cols 0..63, Wb cols 64..127) with row stride ldw.
// Each wave owns 16 rows staged in a private LDS tile (whole K resident).
// Lane owns cols {lane, lane+64}. LDS compute reads are same-address broadcasts.
template <int K>
__global__ __launch_bounds__(256)
void k_gemm(const float* __restrict__ A, int M,
            const float* __restrict__ Wa, const float* __restrict__ Wb, int ldw,
            const float* __restrict__ norm, float* __restrict__ out) {
    constexpr int R = 16;
    constexpr int KV = K / 4;
    __shared__ float lds[4][R * K];
    const int wave = threadIdx.x >> 6;
    const int lane = threadIdx.x & 63;
    const long r0 = ((long)blockIdx.x * 4 + wave) * R;
    const bool active = (r0 < M);

    if (active) {
#pragma unroll
        for (int j = 0; j < (R * KV) / 64; ++j) {
            int v = j * 64 + lane;
            int r = v / KV;
            int kv = v % KV;
            if (r0 + r < M) {
                float4 a = *(const float4*)&A[(r0 + r) * K + 4 * kv];
                *(float4*)&lds[wave][r * K + 4 * kv] = a;
            }
        }
    }
    __syncthreads();
    if (!active) return;

    float acc0[R], acc1[R];
#pragma unroll
    for (int r = 0; r < R; ++r) { acc0[r] = 0.f; acc1[r] = 0.f; }

    const float* lw = lds[wave];
#pragma unroll 2
    for (int kk = 0; kk < K; kk += 4) {
        float wa0 = Wa[(kk + 0) * ldw + lane];
        float wa1 = Wa[(kk + 1) * ldw + lane];
        float wa2 = Wa[(kk + 2) * ldw + lane];
        float wa3 = Wa[(kk + 3) * ldw + lane];
        float wb0 = Wb[(kk + 0) * ldw + lane];
        float wb1 = Wb[(kk + 1) * ldw + lane];
        float wb2 = Wb[(kk + 2) * ldw + lane];
        float wb3 = Wb[(kk + 3) * ldw + lane];
#pragma unroll
        for (int r = 0; r < R; ++r) {
            float4 a = *(const float4*)&lw[r * K + kk];
            acc0[r] = fmaf(a.x, wa0, acc0[r]);
            acc0[r] = fmaf(a.y, wa1, acc0[r]);
            acc0[r] = fmaf(a.z, wa2, acc0[r]);
            acc0[r] = fmaf(a.w, wa3, acc0[r]);
            acc1[r] = fmaf(a.x, wb0, acc1[r]);
            acc1[r] = fmaf(a.y, wb1, acc1[r]);
            acc1[r] = fmaf(a.z, wb2, acc1[r]);
            acc1[r] = fmaf(a.w, wb3, acc1[r]);
        }
    }

#pragma unroll
    for (int r = 0; r < R; ++r) {
        if (r0 + r < M) {
            float nm = norm[r0 + r];
            long o = (r0 + r) * 128;
            out[o + lane] = acc0[r] * nm;
            out[o + 64 + lane] = acc1[r] * nm;
        }
    }
}

// SpMM stage 1: half-wave (32 lanes x float4 = 512B row) per node, register acc.
__global__ __launch_bounds__(256)
void k_spmm_relu(const int* __restrict__ row_off, const int* __restrict__ col,
                 const float* __restrict__ hx, const float* __restrict__ bias,
                 float* __restrict__ h, int N) {
    int g = (blockIdx.x * blockDim.x + threadIdx.x) >> 5;
    int l = threadIdx.x & 31;
    if (g >= N) return;
    int e0 = row_off[g], e1 = row_off[g + 1];
    const float4* base = (const float4*)hx;
    float4 acc = make_float4(0.f, 0.f, 0.f, 0.f);
    int e = e0;
    for (; e + 1 < e1; e += 2) {
        int s0 = col[e], s1 = col[e + 1];
        float4 a = base[(size_t)s0 * 32 + l];
        float4 b = base[(size_t)s1 * 32 + l];
        acc.x += a.x + b.x; acc.y += a.y + b.y;
        acc.z += a.z + b.z; acc.w += a.w + b.w;
    }
    if (e < e1) {
        int s = col[e];
        float4 a = base[(size_t)s * 32 + l];
        acc.x += a.x; acc.y += a.y; acc.z += a.z; acc.w += a.w;
    }
    float4 bi = ((const float4*)bias)[l];
    float4 r;
    r.x = fmaxf(acc.x + bi.x, 0.f);
    r.y = fmaxf(acc.y + bi.y, 0.f);
    r.z = fmaxf(acc.z + bi.z, 0.f);
    r.w = fmaxf(acc.w + bi.w, 0.f);
    ((float4*)h)[(size_t)g * 32 + l] = r;
}

// SpMM stage 2 + reparameterization epilogue.
// Lane l (<16) holds mu cols 4l..4l+3; lane l+16 holds ls cols 64+4l..64+4l+3.
__global__ __launch_bounds__(256)
void k_spmm_out(const int* __restrict__ row_off, const int* __restrict__ col,
                const float* __restrict__ hc, const float* __restrict__ bmu,
                const float* __restrict__ bls, const float* __restrict__ noise,
                float* __restrict__ out, int N) {
    int g = (blockIdx.x * blockDim.x + threadIdx.x) >> 5;
    int l = threadIdx.x & 31;
    if (g >= N) return;
    int e0 = row_off[g], e1 = row_off[g + 1];
    const float4* base = (const float4*)hc;
    float4 acc = make_float4(0.f, 0.f, 0.f, 0.f);
    int e = e0;
    for (; e + 1 < e1; e += 2) {
        int s0 = col[e], s1 = col[e + 1];
        float4 a = base[(size_t)s0 * 32 + l];
        float4 b = base[(size_t)s1 * 32 + l];
        acc.x += a.x + b.x; acc.y += a.y + b.y;
        acc.z += a.z + b.z; acc.w += a.w + b.w;
    }
    if (e < e1) {
        int s = col[e];
        float4 a = base[(size_t)s * 32 + l];
        acc.x += a.x; acc.y += a.y; acc.z += a.z; acc.w += a.w;
    }
    // pull the log_sigma partial from the partner lane (+16 within the half-wave)
    int lane64 = threadIdx.x & 63;
    int p = (lane64 + 16) & 63;
    float lx = __shfl(acc.x, p, 64);
    float ly = __shfl(acc.y, p, 64);
    float lz = __shfl(acc.z, p, 64);
    float lw = __shfl(acc.w, p, 64);
    if (l < 16) {
        float4 bm = ((const float4*)bmu)[l];
        float4 bl = ((const float4*)bls)[l];
        float4 nz = ((const float4*)noise)[(size_t)g * 16 + l];
        float4 o;
        o.x = (acc.x + bm.x) + nz.x * expf(lx + bl.x);
        o.y = (acc.y + bm.y) + nz.y * expf(ly + bl.y);
        o.z = (acc.z + bm.z) + nz.z * expf(lz + bl.z);
        o.w = (acc.w + bm.w) + nz.w * expf(lw + bl.w);
        ((float4*)out)[(size_t)g * 16 + l] = o;
    }
}

extern "C" void kernel_launch(void* const* d_in, const int* in_sizes, int n_in,
                              void* d_out, int out_size, void* d_ws, size_t ws_size,
                              hipStream_t stream) {
    const float* feat  = (const float*)d_in[0];
    const float* Wsh   = (const float*)d_in[1];
    const float* bsh   = (const float*)d_in[2];
    const float* Wmu   = (const float*)d_in[3];
    const float* bmu   = (const float*)d_in[4];
    const float* Wls   = (const float*)d_in[5];
    const float* bls   = (const float*)d_in[6];
    const float* noise = (const float*)d_in[7];
    const int*   src   = (const int*)d_in[8];
    const int*   dst   = (const int*)d_in[9];
    float* out = (float*)d_out;

    const int N = in_sizes[0] / 256;   // 100000
    const int E = in_sizes[8];         // 1600000

    int* deg_out = (int*)d_ws;                       // N
    int* deg_in  = deg_out + N;                      // N
    float* norm  = (float*)(deg_in + N);             // N
    int* row_off = (int*)(norm + N);                 // N+1
    int* fill    = row_off + N + 4;                  // N (pad for 16B align)
    int* col     = fill + N;                         // E
    float* hx    = (float*)(col + E);                // N*128  (also reused as hc)
    float* h     = hx + (size_t)N * 128;             // N*128

    hipMemsetAsync(deg_out, 0, (size_t)2 * N * sizeof(int), stream);

    k_deg<<<(E + 255) / 256, 256, 0, stream>>>(src, dst, deg_out, deg_in, E);
    k_norm<<<(N + 255) / 256, 256, 0, stream>>>(deg_out, norm, N);
    k_scan<<<1, 1024, 0, stream>>>(deg_in, row_off, fill, N);
    k_fill<<<(E + 255) / 256, 256, 0, stream>>>(src, dst, fill, col, E);

    int gemm_blocks = (N + 63) / 64;  // 16 rows/wave * 4 waves/block
    k_gemm<256><<<gemm_blocks, 256, 0, stream>>>(feat, N, Wsh, Wsh + 64, 128, norm, hx);
    k_spmm_relu<<<(N * 32 + 255) / 256, 256, 0, stream>>>(row_off, col, hx, bsh, h, N);
    k_gemm<128><<<gemm_blocks, 256, 0, stream>>>(h, N, Wmu, Wls, 64, norm, hx);
    k_spmm_out<<<(N * 32 + 255) / 256, 256, 0, stream>>>(row_off, col, hx, bmu, bls, noise, out, N);
}

// Round 2
// 912.759 us; speedup vs baseline: 1.2761x; 1.2761x over previous
//
#include <hip/hip_runtime.h>
#include <math.h>

// Pipeline:
//   ws layout: deg_out[N] | deg_in[N] | norm[N] | row_off[N+1(+pad)] | fill[N] |
//              bsum[NB+pad] | boff[NB+1+pad] | col[E] | hx[N*128] | h[N*128]
//   1. memset deg_out/deg_in
//   2. k_deg      : atomic degree histograms (out-deg by src, in-deg by dst)
//   3. k_norm     : norm = 1/max(deg_out,1)
//   4. k_blocksum : per-1024-chunk sums of deg_in          (NB blocks)
//   5. k_scanbsum : 1-block exclusive scan of NB partials  (NB<=1024)
//   6. k_scanfinal: block-local exclusive scan + boff[b] -> row_off, fill
//   7. k_fill     : CSR column fill (src bucketed by dst via atomic slots)
//   8. k_gemm<256>: hx = (feat @ W_shared) * norm[row]
//   9. k_spmm_relu: h[n] = relu(sum_{e in CSR[n]} hx[col[e]] + b_shared)
//  10. k_gemm<128>: hc = (h @ [W_mu | W_ls]) * norm[row]   (into hx buffer)
//  11. k_spmm_out : acc = sum hc rows; out = (acc_mu+b_mu) + noise*exp(acc_ls+b_ls)

__global__ __launch_bounds__(256)
void k_deg(const int* __restrict__ src, const int* __restrict__ dst,
           int* __restrict__ deg_out, int* __restrict__ deg_in, int E) {
    int e = blockIdx.x * blockDim.x + threadIdx.x;
    if (e < E) {
        atomicAdd(&deg_out[src[e]], 1);
        atomicAdd(&deg_in[dst[e]], 1);
    }
}

__global__ __launch_bounds__(256)
void k_norm(const int* __restrict__ deg_out, float* __restrict__ norm, int N) {
    int n = blockIdx.x * blockDim.x + threadIdx.x;
    if (n < N) {
        int d = deg_out[n];
        norm[n] = 1.0f / (float)(d > 1 ? d : 1);
    }
}

// ---- multi-block exclusive scan of deg_in (chunk = 1024 elems / block) ----

__global__ __launch_bounds__(256)
void k_blocksum(const int* __restrict__ deg_in, int* __restrict__ bsum, int N) {
    int t = threadIdx.x;
    int base = blockIdx.x * 1024 + t * 4;
    int s = 0;
    if (base + 3 < N) {
        int4 v = *(const int4*)&deg_in[base];
        s = v.x + v.y + v.z + v.w;
    } else {
        for (int i = 0; i < 4; ++i)
            if (base + i < N) s += deg_in[base + i];
    }
    __shared__ int red[4];
    for (int off = 32; off; off >>= 1) s += __shfl_down(s, off, 64);
    if ((t & 63) == 0) red[t >> 6] = s;
    __syncthreads();
    if (t == 0) bsum[blockIdx.x] = red[0] + red[1] + red[2] + red[3];
}

// One block scans NB (<=1024) block sums; exclusive -> boff; total -> row_off[N].
__global__ __launch_bounds__(1024)
void k_scanbsum(const int* __restrict__ bsum, int* __restrict__ boff,
                int* __restrict__ row_off, int NB, int N) {
    __shared__ int sums[1024];
    int t = threadIdx.x;
    sums[t] = (t < NB) ? bsum[t] : 0;
    __syncthreads();
    for (int off = 1; off < 1024; off <<= 1) {
        int v = (t >= off) ? sums[t - off] : 0;
        __syncthreads();
        sums[t] += v;
        __syncthreads();
    }
    if (t < NB) boff[t] = (t == 0) ? 0 : sums[t - 1];
    if (t == 0) row_off[N] = sums[NB - 1] ? sums[NB - 1] : sums[NB - 1];
    if (t == 0) row_off[N] = sums[NB - 1];
}

// Each block: exclusive scan of its 1024-chunk seeded by boff[b] -> row_off, fill.
__global__ __launch_bounds__(256)
void k_scanfinal(const int* __restrict__ deg_in, const int* __restrict__ boff,
                 int* __restrict__ row_off, int* __restrict__ fill, int N) {
    __shared__ int sums[256];
    int t = threadIdx.x;
    int base = blockIdx.x * 1024 + t * 4;
    int v0 = 0, v1 = 0, v2 = 0, v3 = 0;
    if (base + 3 < N) {
        int4 v = *(const int4*)&deg_in[base];
        v0 = v.x; v1 = v.y; v2 = v.z; v3 = v.w;
    } else {
        if (base + 0 < N) v0 = deg_in[base + 0];
        if (base + 1 < N) v1 = deg_in[base + 1];
        if (base + 2 < N) v2 = deg_in[base + 2];
        if (base + 3 < N) v3 = deg_in[base + 3];
    }
    int ts = v0 + v1 + v2 + v3;
    sums[t] = ts;
    __syncthreads();
    for (int off = 1; off < 256; off <<= 1) {
        int v = (t >= off) ? sums[t - off] : 0;
        __syncthreads();
        sums[t] += v;
        __syncthreads();
    }
    int excl = boff[blockIdx.x] + sums[t] - ts;  // exclusive prefix for this thread
    int p0 = excl, p1 = excl + v0, p2 = excl + v0 + v1, p3 = excl + v0 + v1 + v2;
    if (base + 3 < N) {
        int4 w = make_int4(p0, p1, p2, p3);
        *(int4*)&row_off[base] = w;
        *(int4*)&fill[base] = w;
    } else {
        if (base + 0 < N) { row_off[base + 0] = p0; fill[base + 0] = p0; }
        if (base + 1 < N) { row_off[base + 1] = p1; fill[base + 1] = p1; }
        if (base + 2 < N) { row_off[base + 2] = p2; fill[base + 2] = p2; }
        if (base + 3 < N) { row_off[base + 3] = p3; fill[base + 3] = p3; }
    }
}

__global__ __launch_bounds__(256)
void k_fill(const int* __restrict__ src, const int* __restrict__ dst,
            int* __restrict__ fill, int* __restrict__ col, int E) {
    int e = blockIdx.x * blockDim.x + threadIdx.x;
    if (e < E) {
        int p = atomicAdd(&fill[dst[e]], 1);
        col[p] = src[e];
    }
}

// FP32 GEMM: out[M,128] = (A[M,K] @ W[K,128]) * norm[row]
// W given as two [K,64] halves (Wa cols 0..63, Wb cols 64..127) with row stride ldw.
// Each wave owns 16 rows staged in a private LDS tile (whole K resident).
// Lane owns cols {lane, lane+64}. LDS compute reads are same-address broadcasts.
template <int K>
__global__ __launch_bounds__(256)
void k_gemm(const float* __restrict__ A, int M,
            const float* __restrict__ Wa, const float* __restrict__ Wb, int ldw,
            const float* __restrict__ norm, float* __restrict__ out) {
    constexpr int R = 16;
    constexpr int KV = K / 4;
    __shared__ float lds[4][R * K];
    const int wave = threadIdx.x >> 6;
    const int lane = threadIdx.x & 63;
    const long r0 = ((long)blockIdx.x * 4 + wave) * R;
    const bool active = (r0 < M);

    if (active) {
#pragma unroll
        for (int j = 0; j < (R * KV) / 64; ++j) {
            int v = j * 64 + lane;
            int r = v / KV;
            int kv = v % KV;
            if (r0 + r < M) {
                float4 a = *(const float4*)&A[(r0 + r) * K + 4 * kv];
                *(float4*)&lds[wave][r * K + 4 * kv] = a;
            }
        }
    }
    __syncthreads();
    if (!active) return;

    float acc0[R], acc1[R];
#pragma unroll
    for (int r = 0; r < R; ++r) { acc0[r] = 0.f; acc1[r] = 0.f; }

    const float* lw = lds[wave];
#pragma unroll 2
    for (int kk = 0; kk < K; kk += 4) {
        float wa0 = Wa[(kk + 0) * ldw + lane];
        float wa1 = Wa[(kk + 1) * ldw + lane];
        float wa2 = Wa[(kk + 2) * ldw + lane];
        float wa3 = Wa[(kk + 3) * ldw + lane];
        float wb0 = Wb[(kk + 0) * ldw + lane];
        float wb1 = Wb[(kk + 1) * ldw + lane];
        float wb2 = Wb[(kk + 2) * ldw + lane];
        float wb3 = Wb[(kk + 3) * ldw + lane];
#pragma unroll
        for (int r = 0; r < R; ++r) {
            float4 a = *(const float4*)&lw[r * K + kk];
            acc0[r] = fmaf(a.x, wa0, acc0[r]);
            acc0[r] = fmaf(a.y, wa1, acc0[r]);
            acc0[r] = fmaf(a.z, wa2, acc0[r]);
            acc0[r] = fmaf(a.w, wa3, acc0[r]);
            acc1[r] = fmaf(a.x, wb0, acc1[r]);
            acc1[r] = fmaf(a.y, wb1, acc1[r]);
            acc1[r] = fmaf(a.z, wb2, acc1[r]);
            acc1[r] = fmaf(a.w, wb3, acc1[r]);
        }
    }

#pragma unroll
    for (int r = 0; r < R; ++r) {
        if (r0 + r < M) {
            float nm = norm[r0 + r];
            long o = (r0 + r) * 128;
            out[o + lane] = acc0[r] * nm;
            out[o + 64 + lane] = acc1[r] * nm;
        }
    }
}

// SpMM stage 1: half-wave (32 lanes x float4 = 512B row) per node, register acc.
__global__ __launch_bounds__(256)
void k_spmm_relu(const int* __restrict__ row_off, const int* __restrict__ col,
                 const float* __restrict__ hx, const float* __restrict__ bias,
                 float* __restrict__ h, int N) {
    int g = (blockIdx.x * blockDim.x + threadIdx.x) >> 5;
    int l = threadIdx.x & 31;
    if (g >= N) return;
    int e0 = row_off[g], e1 = row_off[g + 1];
    const float4* base = (const float4*)hx;
    float4 acc = make_float4(0.f, 0.f, 0.f, 0.f);
    int e = e0;
    for (; e + 1 < e1; e += 2) {
        int s0 = col[e], s1 = col[e + 1];
        float4 a = base[(size_t)s0 * 32 + l];
        float4 b = base[(size_t)s1 * 32 + l];
        acc.x += a.x + b.x; acc.y += a.y + b.y;
        acc.z += a.z + b.z; acc.w += a.w + b.w;
    }
    if (e < e1) {
        int s = col[e];
        float4 a = base[(size_t)s * 32 + l];
        acc.x += a.x; acc.y += a.y; acc.z += a.z; acc.w += a.w;
    }
    float4 bi = ((const float4*)bias)[l];
    float4 r;
    r.x = fmaxf(acc.x + bi.x, 0.f);
    r.y = fmaxf(acc.y + bi.y, 0.f);
    r.z = fmaxf(acc.z + bi.z, 0.f);
    r.w = fmaxf(acc.w + bi.w, 0.f);
    ((float4*)h)[(size_t)g * 32 + l] = r;
}

// SpMM stage 2 + reparameterization epilogue.
// Lane l (<16) holds mu cols 4l..4l+3; lane l+16 holds ls cols 64+4l..64+4l+3.
__global__ __launch_bounds__(256)
void k_spmm_out(const int* __restrict__ row_off, const int* __restrict__ col,
                const float* __restrict__ hc, const float* __restrict__ bmu,
                const float* __restrict__ bls, const float* __restrict__ noise,
                float* __restrict__ out, int N) {
    int g = (blockIdx.x * blockDim.x + threadIdx.x) >> 5;
    int l = threadIdx.x & 31;
    if (g >= N) return;
    int e0 = row_off[g], e1 = row_off[g + 1];
    const float4* base = (const float4*)hc;
    float4 acc = make_float4(0.f, 0.f, 0.f, 0.f);
    int e = e0;
    for (; e + 1 < e1; e += 2) {
        int s0 = col[e], s1 = col[e + 1];
        float4 a = base[(size_t)s0 * 32 + l];
        float4 b = base[(size_t)s1 * 32 + l];
        acc.x += a.x + b.x; acc.y += a.y + b.y;
        acc.z += a.z + b.z; acc.w += a.w + b.w;
    }
    if (e < e1) {
        int s = col[e];
        float4 a = base[(size_t)s * 32 + l];
        acc.x += a.x; acc.y += a.y; acc.z += a.z; acc.w += a.w;
    }
    // pull the log_sigma partial from the partner lane (+16 within the half-wave)
    int lane64 = threadIdx.x & 63;
    int p = (lane64 + 16) & 63;
    float lx = __shfl(acc.x, p, 64);
    float ly = __shfl(acc.y, p, 64);
    float lz = __shfl(acc.z, p, 64);
    float lw = __shfl(acc.w, p, 64);
    if (l < 16) {
        float4 bm = ((const float4*)bmu)[l];
        float4 bl = ((const float4*)bls)[l];
        float4 nz = ((const float4*)noise)[(size_t)g * 16 + l];
        float4 o;
        o.x = (acc.x + bm.x) + nz.x * expf(lx + bl.x);
        o.y = (acc.y + bm.y) + nz.y * expf(ly + bl.y);
        o.z = (acc.z + bm.z) + nz.z * expf(lz + bl.z);
        o.w = (acc.w + bm.w) + nz.w * expf(lw + bl.w);
        ((float4*)out)[(size_t)g * 16 + l] = o;
    }
}

extern "C" void kernel_launch(void* const* d_in, const int* in_sizes, int n_in,
                              void* d_out, int out_size, void* d_ws, size_t ws_size,
                              hipStream_t stream) {
    const float* feat  = (const float*)d_in[0];
    const float* Wsh   = (const float*)d_in[1];
    const float* bsh   = (const float*)d_in[2];
    const float* Wmu   = (const float*)d_in[3];
    const float* bmu   = (const float*)d_in[4];
    const float* Wls   = (const float*)d_in[5];
    const float* bls   = (const float*)d_in[6];
    const float* noise = (const float*)d_in[7];
    const int*   src   = (const int*)d_in[8];
    const int*   dst   = (const int*)d_in[9];
    float* out = (float*)d_out;

    const int N = in_sizes[0] / 256;   // 100000
    const int E = in_sizes[8];         // 1600000
    const int NB = (N + 1023) / 1024;  // scan blocks (98)

    int* deg_out = (int*)d_ws;                       // N
    int* deg_in  = deg_out + N;                      // N
    float* norm  = (float*)(deg_in + N);             // N
    int* row_off = (int*)(norm + N);                 // N+1
    int* fill    = row_off + N + 4;                  // N (pad for 16B align)
    int* bsum    = fill + N;                         // NB
    int* boff    = bsum + NB + 4;                    // NB (+pad)
    int* col     = boff + NB + 4;                    // E
    float* hx    = (float*)(col + E);                // N*128  (also reused as hc)
    float* h     = hx + (size_t)N * 128;             // N*128

    hipMemsetAsync(deg_out, 0, (size_t)2 * N * sizeof(int), stream);

    k_deg<<<(E + 255) / 256, 256, 0, stream>>>(src, dst, deg_out, deg_in, E);
    k_norm<<<(N + 255) / 256, 256, 0, stream>>>(deg_out, norm, N);
    k_blocksum<<<NB, 256, 0, stream>>>(deg_in, bsum, N);
    k_scanbsum<<<1, 1024, 0, stream>>>(bsum, boff, row_off, NB, N);
    k_scanfinal<<<NB, 256, 0, stream>>>(deg_in, boff, row_off, fill, N);
    k_fill<<<(E + 255) / 256, 256, 0, stream>>>(src, dst, fill, col, E);

    int gemm_blocks = (N + 63) / 64;  // 16 rows/wave * 4 waves/block
    k_gemm<256><<<gemm_blocks, 256, 0, stream>>>(feat, N, Wsh, Wsh + 64, 128, norm, hx);
    k_spmm_relu<<<(N * 32 + 255) / 256, 256, 0, stream>>>(row_off, col, hx, bsh, h, N);
    k_gemm<128><<<gemm_blocks, 256, 0, stream>>>(h, N, Wmu, Wls, 64, norm, hx);
    k_spmm_out<<<(N * 32 + 255) / 256, 256, 0, stream>>>(row_off, col, hx, bmu, bls, noise, out, N);
}

// Round 3
// 734.683 us; speedup vs baseline: 1.5854x; 1.2424x over previous
//
#include <hip/hip_runtime.h>
#include <math.h>

typedef __attribute__((ext_vector_type(8))) short short8;
typedef __attribute__((ext_vector_type(4))) float f32x4;

// fp32 -> bf16 round-to-nearest-even
__device__ __forceinline__ unsigned short f2bf(float f) {
    unsigned int u = __float_as_uint(f);
    u += 0x7FFF + ((u >> 16) & 1);
    return (unsigned short)(u >> 16);
}
__device__ __forceinline__ float b2f(unsigned short s) {
    return __uint_as_float(((unsigned int)s) << 16);
}

// Pipeline (all intermediates bf16, accumulation fp32):
//   1. k_deg      : atomic degree histograms
//   2. k_norm     : norm = 1/max(deg_out,1)
//   3. k_blocksum / k_scanbsum / k_scanfinal : multi-block exclusive scan -> row_off
//   4. k_fill     : CSR column fill
//   5. k_cvt      : feat fp32 -> featb bf16
//   6. k_gemm_bf16<256>: hx(bf16) = (featb @ Wsh)*norm   [MFMA 16x16x32]
//   7. k_spmm_relu: h(bf16, in d_out scratch) = relu(agg(hx) + b)
//   8. k_gemm_bf16<128>: hc(bf16, in hx buf) = (h @ [Wmu|Wls])*norm
//   9. k_spmm_out : out = (agg_mu+bmu) + noise*exp(agg_ls+bls)

__global__ __launch_bounds__(256)
void k_deg(const int* __restrict__ src, const int* __restrict__ dst,
           int* __restrict__ deg_out, int* __restrict__ deg_in, int E) {
    int e = blockIdx.x * blockDim.x + threadIdx.x;
    if (e < E) {
        atomicAdd(&deg_out[src[e]], 1);
        atomicAdd(&deg_in[dst[e]], 1);
    }
}

__global__ __launch_bounds__(256)
void k_norm(const int* __restrict__ deg_out, float* __restrict__ norm, int N) {
    int n = blockIdx.x * blockDim.x + threadIdx.x;
    if (n < N) {
        int d = deg_out[n];
        norm[n] = 1.0f / (float)(d > 1 ? d : 1);
    }
}

__global__ __launch_bounds__(256)
void k_blocksum(const int* __restrict__ deg_in, int* __restrict__ bsum, int N) {
    int t = threadIdx.x;
    int base = blockIdx.x * 1024 + t * 4;
    int s = 0;
    if (base + 3 < N) {
        int4 v = *(const int4*)&deg_in[base];
        s = v.x + v.y + v.z + v.w;
    } else {
        for (int i = 0; i < 4; ++i)
            if (base + i < N) s += deg_in[base + i];
    }
    __shared__ int red[4];
    for (int off = 32; off; off >>= 1) s += __shfl_down(s, off, 64);
    if ((t & 63) == 0) red[t >> 6] = s;
    __syncthreads();
    if (t == 0) bsum[blockIdx.x] = red[0] + red[1] + red[2] + red[3];
}

__global__ __launch_bounds__(1024)
void k_scanbsum(const int* __restrict__ bsum, int* __restrict__ boff,
                int* __restrict__ row_off, int NB, int N) {
    __shared__ int sums[1024];
    int t = threadIdx.x;
    sums[t] = (t < NB) ? bsum[t] : 0;
    __syncthreads();
    for (int off = 1; off < 1024; off <<= 1) {
        int v = (t >= off) ? sums[t - off] : 0;
        __syncthreads();
        sums[t] += v;
        __syncthreads();
    }
    if (t < NB) boff[t] = (t == 0) ? 0 : sums[t - 1];
    if (t == 0) row_off[N] = sums[NB - 1];
}

__global__ __launch_bounds__(256)
void k_scanfinal(const int* __restrict__ deg_in, const int* __restrict__ boff,
                 int* __restrict__ row_off, int* __restrict__ fill, int N) {
    __shared__ int sums[256];
    int t = threadIdx.x;
    int base = blockIdx.x * 1024 + t * 4;
    int v0 = 0, v1 = 0, v2 = 0, v3 = 0;
    if (base + 3 < N) {
        int4 v = *(const int4*)&deg_in[base];
        v0 = v.x; v1 = v.y; v2 = v.z; v3 = v.w;
    } else {
        if (base + 0 < N) v0 = deg_in[base + 0];
        if (base + 1 < N) v1 = deg_in[base + 1];
        if (base + 2 < N) v2 = deg_in[base + 2];
    }
    int ts = v0 + v1 + v2 + v3;
    sums[t] = ts;
    __syncthreads();
    for (int off = 1; off < 256; off <<= 1) {
        int v = (t >= off) ? sums[t - off] : 0;
        __syncthreads();
        sums[t] += v;
        __syncthreads();
    }
    int excl = boff[blockIdx.x] + sums[t] - ts;
    int p0 = excl, p1 = excl + v0, p2 = excl + v0 + v1, p3 = excl + v0 + v1 + v2;
    if (base + 3 < N) {
        int4 w = make_int4(p0, p1, p2, p3);
        *(int4*)&row_off[base] = w;
        *(int4*)&fill[base] = w;
    } else {
        if (base + 0 < N) { row_off[base + 0] = p0; fill[base + 0] = p0; }
        if (base + 1 < N) { row_off[base + 1] = p1; fill[base + 1] = p1; }
        if (base + 2 < N) { row_off[base + 2] = p2; fill[base + 2] = p2; }
    }
}

__global__ __launch_bounds__(256)
void k_fill(const int* __restrict__ src, const int* __restrict__ dst,
            int* __restrict__ fill, int* __restrict__ col, int E) {
    int e = blockIdx.x * blockDim.x + threadIdx.x;
    if (e < E) {
        int p = atomicAdd(&fill[dst[e]], 1);
        col[p] = src[e];
    }
}

__global__ __launch_bounds__(256)
void k_cvt(const float* __restrict__ in, unsigned short* __restrict__ out, long n4) {
    long i = (long)blockIdx.x * blockDim.x + threadIdx.x;
    if (i < n4) {
        float4 v = ((const float4*)in)[i];
        ushort4 o;
        o.x = f2bf(v.x); o.y = f2bf(v.y); o.z = f2bf(v.z); o.w = f2bf(v.w);
        ((ushort4*)out)[i] = o;
    }
}

// bf16 MFMA GEMM: outb[M,128](bf16) = (A[M,K](bf16) @ W[K,128](fp32)) * norm[row]
// Transposed-operand trick: mfma(Wfrag, Afrag, acc) computes C^T so each lane's
// 4 acc regs are 4 consecutive OUTPUT COLUMNS -> ushort4 store.
//   W-frag (A-operand): W[k][n], n = lane&15 (+tile), k = quad*8+j   [in regs, whole K]
//   A-frag (B-operand): A[m][k], m = lane&15, k = quad*8+j           [global dwordx4]
//   D: lane holds C[m = lane&15 (+16*mtile)][n = quad*4 + reg]
// Grid: x = col-block (0: cols 0..63 from Wa, 1: cols 64..127 from Wb), y = row stride.
template <int K>
__global__ __launch_bounds__(256)
void k_gemm_bf16(const unsigned short* __restrict__ A, int M,
                 const float* __restrict__ Wa, int lda,
                 const float* __restrict__ Wb, int ldb,
                 const float* __restrict__ norm, unsigned short* __restrict__ outb) {
    constexpr int KS = K / 32;
    const int w = threadIdx.x >> 6;
    const int lane = threadIdx.x & 63;
    const int quad = lane >> 4;
    const int l16 = lane & 15;
    const int bx = blockIdx.x;
    const float* Wp = bx ? Wb : Wa;
    const int ld = bx ? ldb : lda;
    const int cl = w * 16 + l16;  // local col within this col-block's 64

    // hoist W fragments for the whole K into registers (converted to bf16)
    short8 bw[KS];
#pragma unroll
    for (int ks = 0; ks < KS; ++ks) {
        union { short8 v; unsigned short u[8]; } c;
#pragma unroll
        for (int j = 0; j < 8; ++j) {
            int k = ks * 32 + quad * 8 + j;
            c.u[j] = f2bf(Wp[(size_t)k * ld + cl]);
        }
        bw[ks] = c.v;
    }

    const int colbase = bx * 64 + w * 16 + quad * 4;

    for (int r0 = blockIdx.y * 64; r0 < M; r0 += gridDim.y * 64) {
        const unsigned short* ap[4];
        int rows[4];
#pragma unroll
        for (int m = 0; m < 4; ++m) {
            int row = r0 + m * 16 + l16;
            rows[m] = row;
            int lr = row < M ? row : M - 1;  // clamp (guarded store below)
            ap[m] = A + (size_t)lr * K + quad * 8;
        }
        f32x4 acc[4];
#pragma unroll
        for (int m = 0; m < 4; ++m) acc[m] = (f32x4){0.f, 0.f, 0.f, 0.f};
#pragma unroll
        for (int ks = 0; ks < KS; ++ks) {
#pragma unroll
            for (int m = 0; m < 4; ++m) {
                short8 af = *(const short8*)(ap[m] + ks * 32);
                acc[m] = __builtin_amdgcn_mfma_f32_16x16x32_bf16(bw[ks], af, acc[m], 0, 0, 0);
            }
        }
#pragma unroll
        for (int m = 0; m < 4; ++m) {
            int row = rows[m];
            if (row < M) {
                float nm = norm[row];
                ushort4 o;
                o.x = f2bf(acc[m][0] * nm);
                o.y = f2bf(acc[m][1] * nm);
                o.z = f2bf(acc[m][2] * nm);
                o.w = f2bf(acc[m][3] * nm);
                *(ushort4*)&outb[(size_t)row * 128 + colbase] = o;
            }
        }
    }
}

// SpMM stage 1: half-wave (32 lanes x ushort4 = 256B bf16 row) per node.
__global__ __launch_bounds__(256)
void k_spmm_relu(const int* __restrict__ row_off, const int* __restrict__ col,
                 const unsigned short* __restrict__ hxb, const float* __restrict__ bias,
                 unsigned short* __restrict__ hb, int N) {
    int g = (blockIdx.x * blockDim.x + threadIdx.x) >> 5;
    int l = threadIdx.x & 31;
    if (g >= N) return;
    int e0 = row_off[g], e1 = row_off[g + 1];
    const ushort4* base = (const ushort4*)hxb;
    float4 acc = make_float4(0.f, 0.f, 0.f, 0.f);
    int e = e0;
    for (; e + 1 < e1; e += 2) {
        ushort4 a = base[(size_t)col[e] * 32 + l];
        ushort4 b = base[(size_t)col[e + 1] * 32 + l];
        acc.x += b2f(a.x) + b2f(b.x);
        acc.y += b2f(a.y) + b2f(b.y);
        acc.z += b2f(a.z) + b2f(b.z);
        acc.w += b2f(a.w) + b2f(b.w);
    }
    if (e < e1) {
        ushort4 a = base[(size_t)col[e] * 32 + l];
        acc.x += b2f(a.x); acc.y += b2f(a.y); acc.z += b2f(a.z); acc.w += b2f(a.w);
    }
    float4 bi = ((const float4*)bias)[l];
    ushort4 r;
    r.x = f2bf(fmaxf(acc.x + bi.x, 0.f));
    r.y = f2bf(fmaxf(acc.y + bi.y, 0.f));
    r.z = f2bf(fmaxf(acc.z + bi.z, 0.f));
    r.w = f2bf(fmaxf(acc.w + bi.w, 0.f));
    ((ushort4*)hb)[(size_t)g * 32 + l] = r;
}

// SpMM stage 2 + reparameterization. Lane l<16: mu cols 4l..4l+3; lane l+16: ls.
__global__ __launch_bounds__(256)
void k_spmm_out(const int* __restrict__ row_off, const int* __restrict__ col,
                const unsigned short* __restrict__ hcb, const float* __restrict__ bmu,
                const float* __restrict__ bls, const float* __restrict__ noise,
                float* __restrict__ out, int N) {
    int g = (blockIdx.x * blockDim.x + threadIdx.x) >> 5;
    int l = threadIdx.x & 31;
    if (g >= N) return;
    int e0 = row_off[g], e1 = row_off[g + 1];
    const ushort4* base = (const ushort4*)hcb;
    float4 acc = make_float4(0.f, 0.f, 0.f, 0.f);
    int e = e0;
    for (; e + 1 < e1; e += 2) {
        ushort4 a = base[(size_t)col[e] * 32 + l];
        ushort4 b = base[(size_t)col[e + 1] * 32 + l];
        acc.x += b2f(a.x) + b2f(b.x);
        acc.y += b2f(a.y) + b2f(b.y);
        acc.z += b2f(a.z) + b2f(b.z);
        acc.w += b2f(a.w) + b2f(b.w);
    }
    if (e < e1) {
        ushort4 a = base[(size_t)col[e] * 32 + l];
        acc.x += b2f(a.x); acc.y += b2f(a.y); acc.z += b2f(a.z); acc.w += b2f(a.w);
    }
    int lane64 = threadIdx.x & 63;
    int p = (lane64 + 16) & 63;
    float lx = __shfl(acc.x, p, 64);
    float ly = __shfl(acc.y, p, 64);
    float lz = __shfl(acc.z, p, 64);
    float lw = __shfl(acc.w, p, 64);
    if (l < 16) {
        float4 bm = ((const float4*)bmu)[l];
        float4 bl = ((const float4*)bls)[l];
        float4 nz = ((const float4*)noise)[(size_t)g * 16 + l];
        float4 o;
        o.x = (acc.x + bm.x) + nz.x * expf(lx + bl.x);
        o.y = (acc.y + bm.y) + nz.y * expf(ly + bl.y);
        o.z = (acc.z + bm.z) + nz.z * expf(lz + bl.z);
        o.w = (acc.w + bm.w) + nz.w * expf(lw + bl.w);
        ((float4*)out)[(size_t)g * 16 + l] = o;
    }
}

extern "C" void kernel_launch(void* const* d_in, const int* in_sizes, int n_in,
                              void* d_out, int out_size, void* d_ws, size_t ws_size,
                              hipStream_t stream) {
    const float* feat  = (const float*)d_in[0];
    const float* Wsh   = (const float*)d_in[1];
    const float* bsh   = (const float*)d_in[2];
    const float* Wmu   = (const float*)d_in[3];
    const float* bmu   = (const float*)d_in[4];
    const float* Wls   = (const float*)d_in[5];
    const float* bls   = (const float*)d_in[6];
    const float* noise = (const float*)d_in[7];
    const int*   src   = (const int*)d_in[8];
    const int*   dst   = (const int*)d_in[9];
    float* out = (float*)d_out;

    const int N = in_sizes[0] / 256;   // 100000
    const int E = in_sizes[8];         // 1600000
    const int NB = (N + 1023) / 1024;  // 98

    int* deg_out = (int*)d_ws;                       // N
    int* deg_in  = deg_out + N;                      // N
    float* norm  = (float*)(deg_in + N);             // N
    int* row_off = (int*)(norm + N);                 // N+1
    int* fill    = row_off + N + 4;                  // N
    int* bsum    = fill + N;                         // NB
    int* boff    = bsum + NB + 4;                    // NB
    int* col     = boff + NB + 4;                    // E
    unsigned short* featb = (unsigned short*)(((uintptr_t)(col + E) + 63) & ~(uintptr_t)63);  // N*256 bf16
    unsigned short* hxb   = featb + (size_t)N * 256; // N*128 bf16 (hx, then hc)
    unsigned short* hb    = (unsigned short*)d_out;  // N*128 bf16 scratch (=25.6MB, exact fit)

    hipMemsetAsync(deg_out, 0, (size_t)2 * N * sizeof(int), stream);

    k_deg<<<(E + 255) / 256, 256, 0, stream>>>(src, dst, deg_out, deg_in, E);
    k_norm<<<(N + 255) / 256, 256, 0, stream>>>(deg_out, norm, N);
    k_blocksum<<<NB, 256, 0, stream>>>(deg_in, bsum, N);
    k_scanbsum<<<1, 1024, 0, stream>>>(bsum, boff, row_off, NB, N);
    k_scanfinal<<<NB, 256, 0, stream>>>(deg_in, boff, row_off, fill, N);
    k_fill<<<(E + 255) / 256, 256, 0, stream>>>(src, dst, fill, col, E);

    long n4 = (long)N * 64;  // N*256/4
    k_cvt<<<(int)((n4 + 255) / 256), 256, 0, stream>>>(feat, featb, n4);

    k_gemm_bf16<256><<<dim3(2, 256), 256, 0, stream>>>(featb, N, Wsh, 128, Wsh + 64, 128, norm, hxb);
    k_spmm_relu<<<(N * 32 + 255) / 256, 256, 0, stream>>>(row_off, col, hxb, bsh, hb, N);
    k_gemm_bf16<128><<<dim3(2, 256), 256, 0, stream>>>(hb, N, Wmu, 64, Wls, 64, norm, hxb);
    k_spmm_out<<<(N * 32 + 255) / 256, 256, 0, stream>>>(row_off, col, hxb, bmu, bls, noise, out, N);
}

// Round 4
// 605.513 us; speedup vs baseline: 1.9237x; 1.2133x over previous
//
#include <hip/hip_runtime.h>
#include <math.h>

typedef __attribute__((ext_vector_type(8))) short short8;
typedef __attribute__((ext_vector_type(4))) float f32x4;

// fp32 -> bf16 round-to-nearest-even
__device__ __forceinline__ unsigned short f2bf(float f) {
    unsigned int u = __float_as_uint(f);
    u += 0x7FFF + ((u >> 16) & 1);
    return (unsigned short)(u >> 16);
}
__device__ __forceinline__ float b2f(unsigned short s) {
    return __uint_as_float(((unsigned int)s) << 16);
}

// CSR build via LDS two-level bucket sort, ZERO global atomics.
//   bucket(node) = node >> 7  (128 nodes/bucket; 1024 buckets cover N<=131072)
//   bins: 0..1023 = dst buckets (CSR), 1024..2047 = src buckets (out-degree)
#define EB 8192  // edges per partition block

__global__ __launch_bounds__(256)
void k1_hist(const int* __restrict__ src, const int* __restrict__ dst,
             int* __restrict__ bhist, int E) {
    __shared__ int hist[2048];
    int t = threadIdx.x;
    for (int i = t; i < 2048; i += 256) hist[i] = 0;
    __syncthreads();
    int base = blockIdx.x * EB;
    int end = min(base + EB, E);
    for (int e = base + t; e < end; e += 256) {
        atomicAdd(&hist[dst[e] >> 7], 1);
        atomicAdd(&hist[1024 + (src[e] >> 7)], 1);
    }
    __syncthreads();
    int* o = bhist + (size_t)blockIdx.x * 2048;
    for (int i = t; i < 2048; i += 256) o[i] = hist[i];
}

__global__ __launch_bounds__(256)
void kc1_totals(const int* __restrict__ bhist, int* __restrict__ totals, int PB) {
    int b = blockIdx.x * 256 + threadIdx.x;  // 0..2047
    int s = 0;
    for (int blk = 0; blk < PB; ++blk) s += bhist[(size_t)blk * 2048 + b];
    totals[b] = s;
}

__global__ __launch_bounds__(1024)
void kc2_scan(const int* __restrict__ in, int* __restrict__ out, int n) {
    __shared__ int sums[1024];
    int t = threadIdx.x;
    int v = (t < n) ? in[t] : 0;
    sums[t] = v;
    __syncthreads();
    for (int off = 1; off < 1024; off <<= 1) {
        int u = (t >= off) ? sums[t - off] : 0;
        __syncthreads();
        sums[t] += u;
        __syncthreads();
    }
    if (t < n) out[t] = sums[t] - v;
}

__global__ __launch_bounds__(256)
void kc3_boff(const int* __restrict__ bhist, const int* __restrict__ bbase_d,
              const int* __restrict__ bbase_s, int* __restrict__ boffT, int PB) {
    __shared__ int sums[256];
    int b = blockIdx.x;  // 0..2047
    int t = threadIdx.x;
    int v = (t < PB) ? bhist[(size_t)t * 2048 + b] : 0;
    sums[t] = v;
    __syncthreads();
    for (int off = 1; off < 256; off <<= 1) {
        int u = (t >= off) ? sums[t - off] : 0;
        __syncthreads();
        sums[t] += u;
        __syncthreads();
    }
    int base = (b < 1024) ? bbase_d[b] : bbase_s[b - 1024];
    if (t < PB) boffT[(size_t)b * PB + t] = base + sums[t] - v;
}

__global__ __launch_bounds__(256)
void k2_scatter(const int* __restrict__ src, const int* __restrict__ dst,
                const int* __restrict__ boffT, int2* __restrict__ parr,
                int* __restrict__ sarr, int E, int PB) {
    __shared__ int cnt[2048];
    int t = threadIdx.x;
    int blk = blockIdx.x;
    for (int i = t; i < 2048; i += 256) cnt[i] = boffT[(size_t)i * PB + blk];
    __syncthreads();
    int base = blk * EB;
    int end = min(base + EB, E);
    for (int e = base + t; e < end; e += 256) {
        int s = src[e], d = dst[e];
        int pd = atomicAdd(&cnt[d >> 7], 1);
        parr[pd] = make_int2(s, d);
        int ps = atomicAdd(&cnt[1024 + (s >> 7)], 1);
        sarr[ps] = s;
    }
}

__global__ __launch_bounds__(256)
void k3_dst(const int2* __restrict__ parr, const int* __restrict__ totals,
            const int* __restrict__ bbase_d, int* __restrict__ row_off,
            int* __restrict__ col, int N, int E) {
    __shared__ int hist[128], cnt[128], sc[128];
    int b = blockIdx.x, t = threadIdx.x;
    if (b == 0 && t == 0) row_off[N] = E;
    int ne = totals[b];
    int ebase = bbase_d[b];
    if (t < 128) hist[t] = 0;
    __syncthreads();
    for (int i = t; i < ne; i += 256)
        atomicAdd(&hist[parr[ebase + i].y & 127], 1);
    __syncthreads();
    int h = (t < 128) ? hist[t] : 0;
    if (t < 128) sc[t] = h;
    __syncthreads();
    for (int off = 1; off < 128; off <<= 1) {
        int u = (t < 128 && t >= off) ? sc[t - off] : 0;
        __syncthreads();
        if (t < 128) sc[t] += u;
        __syncthreads();
    }
    if (t < 128) {
        int excl = sc[t] - h;
        cnt[t] = ebase + excl;
        int node = b * 128 + t;
        if (node < N) row_off[node] = ebase + excl;
    }
    __syncthreads();
    for (int i = t; i < ne; i += 256) {
        int2 pr = parr[ebase + i];
        int slot = atomicAdd(&cnt[pr.y & 127], 1);
        col[slot] = pr.x;
    }
}

__global__ __launch_bounds__(256)
void k3_src(const int* __restrict__ sarr, const int* __restrict__ totals_s,
            const int* __restrict__ bbase_s, float* __restrict__ norm, int N) {
    __shared__ int hist[128];
    int b = blockIdx.x, t = threadIdx.x;
    int ne = totals_s[b];
    int sb = bbase_s[b];
    if (t < 128) hist[t] = 0;
    __syncthreads();
    for (int i = t; i < ne; i += 256)
        atomicAdd(&hist[sarr[sb + i] & 127], 1);
    __syncthreads();
    if (t < 128) {
        int node = b * 128 + t;
        if (node < N) {
            int d = hist[t];
            norm[node] = 1.0f / (float)(d > 1 ? d : 1);
        }
    }
}

__global__ __launch_bounds__(256)
void k_cvt(const float* __restrict__ in, unsigned short* __restrict__ out, long n4) {
    long i = (long)blockIdx.x * blockDim.x + threadIdx.x;
    if (i < n4) {
        float4 v = ((const float4*)in)[i];
        ushort4 o;
        o.x = f2bf(v.x); o.y = f2bf(v.y); o.z = f2bf(v.z); o.w = f2bf(v.w);
        ((ushort4*)out)[i] = o;
    }
}

// bf16 MFMA GEMM: outb[M,128](bf16) = (A[M,K](bf16) @ W[K,128](fp32)) * norm[row]
// Transposed-operand trick: mfma(Wfrag, Afrag, acc) computes C^T so lane's 4 acc
// regs are 4 consecutive OUTPUT COLUMNS -> ushort4 store.
template <int K>
__global__ __launch_bounds__(256)
void k_gemm_bf16(const unsigned short* __restrict__ A, int M,
                 const float* __restrict__ Wa, int lda,
                 const float* __restrict__ Wb, int ldb,
                 const float* __restrict__ norm, unsigned short* __restrict__ outb) {
    constexpr int KS = K / 32;
    const int w = threadIdx.x >> 6;
    const int lane = threadIdx.x & 63;
    const int quad = lane >> 4;
    const int l16 = lane & 15;
    const int bx = blockIdx.x;
    const float* Wp = bx ? Wb : Wa;
    const int ld = bx ? ldb : lda;
    const int cl = w * 16 + l16;

    short8 bw[KS];
#pragma unroll
    for (int ks = 0; ks < KS; ++ks) {
        union { short8 v; unsigned short u[8]; } c;
#pragma unroll
        for (int j = 0; j < 8; ++j) {
            int k = ks * 32 + quad * 8 + j;
            c.u[j] = f2bf(Wp[(size_t)k * ld + cl]);
        }
        bw[ks] = c.v;
    }

    const int colbase = bx * 64 + w * 16 + quad * 4;

    for (int r0 = blockIdx.y * 64; r0 < M; r0 += gridDim.y * 64) {
        const unsigned short* ap[4];
        int rows[4];
#pragma unroll
        for (int m = 0; m < 4; ++m) {
            int row = r0 + m * 16 + l16;
            rows[m] = row;
            int lr = row < M ? row : M - 1;
            ap[m] = A + (size_t)lr * K + quad * 8;
        }
        f32x4 acc[4];
#pragma unroll
        for (int m = 0; m < 4; ++m) acc[m] = (f32x4){0.f, 0.f, 0.f, 0.f};
#pragma unroll
        for (int ks = 0; ks < KS; ++ks) {
#pragma unroll
            for (int m = 0; m < 4; ++m) {
                short8 af = *(const short8*)(ap[m] + ks * 32);
                acc[m] = __builtin_amdgcn_mfma_f32_16x16x32_bf16(bw[ks], af, acc[m], 0, 0, 0);
            }
        }
#pragma unroll
        for (int m = 0; m < 4; ++m) {
            int row = rows[m];
            if (row < M) {
                float nm = norm[row];
                ushort4 o;
                o.x = f2bf(acc[m][0] * nm);
                o.y = f2bf(acc[m][1] * nm);
                o.z = f2bf(acc[m][2] * nm);
                o.w = f2bf(acc[m][3] * nm);
                *(ushort4*)&outb[(size_t)row * 128 + colbase] = o;
            }
        }
    }
}

// SpMM stage 1: half-wave (32 lanes x ushort4 = 256B bf16 row) per node.
__global__ __launch_bounds__(256)
void k_spmm_relu(const int* __restrict__ row_off, const int* __restrict__ col,
                 const unsigned short* __restrict__ hxb, const float* __restrict__ bias,
                 unsigned short* __restrict__ hb, int N) {
    int g = (blockIdx.x * blockDim.x + threadIdx.x) >> 5;
    int l = threadIdx.x & 31;
    if (g >= N) return;
    int e0 = row_off[g], e1 = row_off[g + 1];
    const ushort4* base = (const ushort4*)hxb;
    float4 acc = make_float4(0.f, 0.f, 0.f, 0.f);
    int e = e0;
    for (; e + 1 < e1; e += 2) {
        ushort4 a = base[(size_t)col[e] * 32 + l];
        ushort4 b = base[(size_t)col[e + 1] * 32 + l];
        acc.x += b2f(a.x) + b2f(b.x);
        acc.y += b2f(a.y) + b2f(b.y);
        acc.z += b2f(a.z) + b2f(b.z);
        acc.w += b2f(a.w) + b2f(b.w);
    }
    if (e < e1) {
        ushort4 a = base[(size_t)col[e] * 32 + l];
        acc.x += b2f(a.x); acc.y += b2f(a.y); acc.z += b2f(a.z); acc.w += b2f(a.w);
    }
    float4 bi = ((const float4*)bias)[l];
    ushort4 r;
    r.x = f2bf(fmaxf(acc.x + bi.x, 0.f));
    r.y = f2bf(fmaxf(acc.y + bi.y, 0.f));
    r.z = f2bf(fmaxf(acc.z + bi.z, 0.f));
    r.w = f2bf(fmaxf(acc.w + bi.w, 0.f));
    ((ushort4*)hb)[(size_t)g * 32 + l] = r;
}

// SpMM stage 2 + reparameterization. Lane l<16: mu cols 4l..4l+3; lane l+16: ls.
__global__ __launch_bounds__(256)
void k_spmm_out(const int* __restrict__ row_off, const int* __restrict__ col,
                const unsigned short* __restrict__ hcb, const float* __restrict__ bmu,
                const float* __restrict__ bls, const float* __restrict__ noise,
                float* __restrict__ out, int N) {
    int g = (blockIdx.x * blockDim.x + threadIdx.x) >> 5;
    int l = threadIdx.x & 31;
    if (g >= N) return;
    int e0 = row_off[g], e1 = row_off[g + 1];
    const ushort4* base = (const ushort4*)hcb;
    float4 acc = make_float4(0.f, 0.f, 0.f, 0.f);
    int e = e0;
    for (; e + 1 < e1; e += 2) {
        ushort4 a = base[(size_t)col[e] * 32 + l];
        ushort4 b = base[(size_t)col[e + 1] * 32 + l];
        acc.x += b2f(a.x) + b2f(b.x);
        acc.y += b2f(a.y) + b2f(b.y);
        acc.z += b2f(a.z) + b2f(b.z);
        acc.w += b2f(a.w) + b2f(b.w);
    }
    if (e < e1) {
        ushort4 a = base[(size_t)col[e] * 32 + l];
        acc.x += b2f(a.x); acc.y += b2f(a.y); acc.z += b2f(a.z); acc.w += b2f(a.w);
    }
    int lane64 = threadIdx.x & 63;
    int p = (lane64 + 16) & 63;
    float lx = __shfl(acc.x, p, 64);
    float ly = __shfl(acc.y, p, 64);
    float lz = __shfl(acc.z, p, 64);
    float lw = __shfl(acc.w, p, 64);
    if (l < 16) {
        float4 bm = ((const float4*)bmu)[l];
        float4 bl = ((const float4*)bls)[l];
        float4 nz = ((const float4*)noise)[(size_t)g * 16 + l];
        float4 o;
        o.x = (acc.x + bm.x) + nz.x * expf(lx + bl.x);
        o.y = (acc.y + bm.y) + nz.y * expf(ly + bl.y);
        o.z = (acc.z + bm.z) + nz.z * expf(lz + bl.z);
        o.w = (acc.w + bm.w) + nz.w * expf(lw + bl.w);
        ((float4*)out)[(size_t)g * 16 + l] = o;
    }
}

static inline char* align64(char* p) {
    return (char*)(((uintptr_t)p + 63) & ~(uintptr_t)63);
}

extern "C" void kernel_launch(void* const* d_in, const int* in_sizes, int n_in,
                              void* d_out, int out_size, void* d_ws, size_t ws_size,
                              hipStream_t stream) {
    const float* feat  = (const float*)d_in[0];
    const float* Wsh   = (const float*)d_in[1];
    const float* bsh   = (const float*)d_in[2];
    const float* Wmu   = (const float*)d_in[3];
    const float* bmu   = (const float*)d_in[4];
    const float* Wls   = (const float*)d_in[5];
    const float* bls   = (const float*)d_in[6];
    const float* noise = (const float*)d_in[7];
    const int*   src   = (const int*)d_in[8];
    const int*   dst   = (const int*)d_in[9];
    float* out = (float*)d_out;

    const int N = in_sizes[0] / 256;   // 100000 (<= 131072 for 1024 buckets)
    const int E = in_sizes[8];         // 1600000
    const int PB = (E + EB - 1) / EB;  // 196

    char* p = (char*)d_ws;
    float* norm   = (float*)p;                  p += (size_t)N * 4;         p = align64(p);
    int* row_off  = (int*)p;                    p += (size_t)(N + 4) * 4;   p = align64(p);
    int* totals   = (int*)p;                    p += 2048 * 4;
    int* bbase_d  = (int*)p;                    p += 1024 * 4;
    int* bbase_s  = (int*)p;                    p += 1024 * 4;              p = align64(p);
    int* bhist    = (int*)p;                    p += (size_t)PB * 2048 * 4; p = align64(p);
    int* boffT    = (int*)p;                    p += (size_t)2048 * PB * 4; p = align64(p);
    int2* parr    = (int2*)p;                   p += (size_t)E * 8;
    int* sarr     = (int*)p;                    p += (size_t)E * 4;
    int* col      = (int*)p;                    p += (size_t)E * 4;         p = align64(p);
    unsigned short* featb = (unsigned short*)p; p += (size_t)N * 256 * 2;
    unsigned short* hxb   = (unsigned short*)p;                 // N*128 bf16
    unsigned short* hb    = (unsigned short*)d_out;             // N*128 bf16 scratch

    // ---- CSR build (no global atomics) ----
    k1_hist<<<PB, 256, 0, stream>>>(src, dst, bhist, E);
    kc1_totals<<<8, 256, 0, stream>>>(bhist, totals, PB);
    kc2_scan<<<1, 1024, 0, stream>>>(totals, bbase_d, 1024);
    kc2_scan<<<1, 1024, 0, stream>>>(totals + 1024, bbase_s, 1024);
    kc3_boff<<<2048, 256, 0, stream>>>(bhist, bbase_d, bbase_s, boffT, PB);
    k2_scatter<<<PB, 256, 0, stream>>>(src, dst, boffT, parr, sarr, E, PB);
    k3_dst<<<1024, 256, 0, stream>>>(parr, totals, bbase_d, row_off, col, N, E);
    k3_src<<<1024, 256, 0, stream>>>(sarr, totals + 1024, bbase_s, norm, N);

    // ---- dense pipeline ----
    long n4 = (long)N * 64;
    k_cvt<<<(int)((n4 + 255) / 256), 256, 0, stream>>>(feat, featb, n4);
    k_gemm_bf16<256><<<dim3(2, 256), 256, 0, stream>>>(featb, N, Wsh, 128, Wsh + 64, 128, norm, hxb);
    k_spmm_relu<<<(N * 32 + 255) / 256, 256, 0, stream>>>(row_off, col, hxb, bsh, hb, N);
    k_gemm_bf16<128><<<dim3(2, 256), 256, 0, stream>>>(hb, N, Wmu, 64, Wls, 64, norm, hxb);
    k_spmm_out<<<(N * 32 + 255) / 256, 256, 0, stream>>>(row_off, col, hxb, bmu, bls, noise, out, N);
}

// Round 5
// 529.141 us; speedup vs baseline: 2.2013x; 1.1443x over previous
//
#include <hip/hip_runtime.h>
#include <math.h>

typedef __attribute__((ext_vector_type(8))) short short8;
typedef __attribute__((ext_vector_type(4))) float f32x4;

// fp32 -> bf16 round-to-nearest-even
__device__ __forceinline__ unsigned short f2bf(float f) {
    unsigned int u = __float_as_uint(f);
    u += 0x7FFF + ((u >> 16) & 1);
    return (unsigned short)(u >> 16);
}
__device__ __forceinline__ float b2f(unsigned short s) {
    return __uint_as_float(((unsigned int)s) << 16);
}

// CSR build via LDS two-level bucket sort, ZERO global atomics.
// COARSE buckets: 128 buckets x 1024 nodes (covers N<=131072).
//   bins: 0..127 = dst buckets (CSR), 128..255 = src buckets (out-degree)
// Coarse buckets give ~64-edge (512B) runs per (block,bucket) in the scatter
// -> near-1x write amplification (R4's 1024 fine buckets gave 8-edge runs and
//    thrashed L2 with 64B-line-per-8B writes).
#define EB 8192        // edges per partition block
#define BSH 10         // node >> 10 = bucket
#define NBKT 128

__global__ __launch_bounds__(256)
void k1_hist(const int* __restrict__ src, const int* __restrict__ dst,
             int* __restrict__ bhist, int E) {
    __shared__ int hist[256];
    int t = threadIdx.x;
    hist[t] = 0;
    __syncthreads();
    int base = blockIdx.x * EB;
    int end = min(base + EB, E);
    for (int e = base + 4 * t; e < end; e += 1024) {
        if (e + 3 < end) {
            int4 d4 = *(const int4*)&dst[e];
            int4 s4 = *(const int4*)&src[e];
            atomicAdd(&hist[d4.x >> BSH], 1);
            atomicAdd(&hist[d4.y >> BSH], 1);
            atomicAdd(&hist[d4.z >> BSH], 1);
            atomicAdd(&hist[d4.w >> BSH], 1);
            atomicAdd(&hist[128 + (s4.x >> BSH)], 1);
            atomicAdd(&hist[128 + (s4.y >> BSH)], 1);
            atomicAdd(&hist[128 + (s4.z >> BSH)], 1);
            atomicAdd(&hist[128 + (s4.w >> BSH)], 1);
        } else {
            for (int q = e; q < end; ++q) {
                atomicAdd(&hist[dst[q] >> BSH], 1);
                atomicAdd(&hist[128 + (src[q] >> BSH)], 1);
            }
        }
    }
    __syncthreads();
    bhist[(size_t)blockIdx.x * 256 + t] = hist[t];
}

// 8 blocks, each sums a PB-slice for all 256 bins; atomic into zeroed totals.
__global__ __launch_bounds__(256)
void kc1_totals(const int* __restrict__ bhist, int* __restrict__ totals, int PB) {
    int t = threadIdx.x;
    int slice = (PB + 7) / 8;
    int b0 = blockIdx.x * slice;
    int b1 = min(b0 + slice, PB);
    int s = 0;
    for (int blk = b0; blk < b1; ++blk) s += bhist[(size_t)blk * 256 + t];
    if (s) atomicAdd(&totals[t], s);
}

// Segmented exclusive scan: bins 0..127 (dst) and 128..255 (src) independently.
__global__ __launch_bounds__(256)
void kc2_scan2(const int* __restrict__ totals, int* __restrict__ bbase_d,
               int* __restrict__ bbase_s) {
    __shared__ int s[256];
    int t = threadIdx.x;
    int v = totals[t];
    s[t] = v;
    __syncthreads();
    for (int off = 1; off < 128; off <<= 1) {
        int u = ((t & 127) >= off) ? s[t - off] : 0;
        __syncthreads();
        s[t] += u;
        __syncthreads();
    }
    int excl = s[t] - v;
    if (t < 128) bbase_d[t] = excl;
    else bbase_s[t - 128] = excl;
}

// Per-bin scan over partition blocks -> scatter offsets boffT[bin][PB].
__global__ __launch_bounds__(256)
void kc3_boff(const int* __restrict__ bhist, const int* __restrict__ bbase_d,
              const int* __restrict__ bbase_s, int* __restrict__ boffT, int PB) {
    __shared__ int sums[256];
    int b = blockIdx.x;  // 0..255
    int t = threadIdx.x;
    int v = (t < PB) ? bhist[(size_t)t * 256 + b] : 0;
    sums[t] = v;
    __syncthreads();
    for (int off = 1; off < 256; off <<= 1) {
        int u = (t >= off) ? sums[t - off] : 0;
        __syncthreads();
        sums[t] += u;
        __syncthreads();
    }
    int base = (b < 128) ? bbase_d[b] : bbase_s[b - 128];
    if (t < PB) boffT[(size_t)b * PB + t] = base + sums[t] - v;
}

__global__ __launch_bounds__(256)
void k2_scatter(const int* __restrict__ src, const int* __restrict__ dst,
                const int* __restrict__ boffT, int2* __restrict__ parr,
                int* __restrict__ sarr, int E, int PB) {
    __shared__ int cnt[256];
    int t = threadIdx.x;
    int blk = blockIdx.x;
    cnt[t] = boffT[(size_t)t * PB + blk];
    __syncthreads();
    int base = blk * EB;
    int end = min(base + EB, E);
    for (int e = base + 4 * t; e < end; e += 1024) {
        if (e + 3 < end) {
            int4 s4 = *(const int4*)&src[e];
            int4 d4 = *(const int4*)&dst[e];
            int p0 = atomicAdd(&cnt[d4.x >> BSH], 1); parr[p0] = make_int2(s4.x, d4.x);
            int p1 = atomicAdd(&cnt[d4.y >> BSH], 1); parr[p1] = make_int2(s4.y, d4.y);
            int p2 = atomicAdd(&cnt[d4.z >> BSH], 1); parr[p2] = make_int2(s4.z, d4.z);
            int p3 = atomicAdd(&cnt[d4.w >> BSH], 1); parr[p3] = make_int2(s4.w, d4.w);
            int q0 = atomicAdd(&cnt[128 + (s4.x >> BSH)], 1); sarr[q0] = s4.x;
            int q1 = atomicAdd(&cnt[128 + (s4.y >> BSH)], 1); sarr[q1] = s4.y;
            int q2 = atomicAdd(&cnt[128 + (s4.z >> BSH)], 1); sarr[q2] = s4.z;
            int q3 = atomicAdd(&cnt[128 + (s4.w >> BSH)], 1); sarr[q3] = s4.w;
        } else {
            for (int q = e; q < end; ++q) {
                int sv = src[q], dv = dst[q];
                int pd = atomicAdd(&cnt[dv >> BSH], 1);
                parr[pd] = make_int2(sv, dv);
                int ps = atomicAdd(&cnt[128 + (sv >> BSH)], 1);
                sarr[ps] = sv;
            }
        }
    }
}

// Per dst-bucket (1024 nodes): LDS 1024-bin hist + scan -> row_off, col.
__global__ __launch_bounds__(1024)
void k3_dst(const int2* __restrict__ parr, const int* __restrict__ totals,
            const int* __restrict__ bbase_d, int* __restrict__ row_off,
            int* __restrict__ col, int N, int E) {
    __shared__ int hist[1024], sc[1024];
    int b = blockIdx.x, t = threadIdx.x;
    if (b == 0 && t == 0) row_off[N] = E;
    int ne = totals[b];
    int ebase = bbase_d[b];
    hist[t] = 0;
    __syncthreads();
    for (int i = t; i < ne; i += 1024)
        atomicAdd(&hist[parr[ebase + i].y & 1023], 1);
    __syncthreads();
    int h = hist[t];
    sc[t] = h;
    __syncthreads();
    for (int off = 1; off < 1024; off <<= 1) {
        int u = (t >= off) ? sc[t - off] : 0;
        __syncthreads();
        sc[t] += u;
        __syncthreads();
    }
    int excl = sc[t] - h;
    int node = b * 1024 + t;
    if (node < N) row_off[node] = ebase + excl;
    hist[t] = ebase + excl;  // reuse as scatter counters
    __syncthreads();
    for (int i = t; i < ne; i += 1024) {
        int2 pr = parr[ebase + i];
        int slot = atomicAdd(&hist[pr.y & 1023], 1);
        col[slot] = pr.x;
    }
}

// Per src-bucket: LDS hist of out-degrees -> norm = 1/max(deg,1).
__global__ __launch_bounds__(1024)
void k3_src(const int* __restrict__ sarr, const int* __restrict__ totals_s,
            const int* __restrict__ bbase_s, float* __restrict__ norm, int N) {
    __shared__ int hist[1024];
    int b = blockIdx.x, t = threadIdx.x;
    int ne = totals_s[b];
    int sb = bbase_s[b];
    hist[t] = 0;
    __syncthreads();
    for (int i = t; i < ne; i += 1024)
        atomicAdd(&hist[sarr[sb + i] & 1023], 1);
    __syncthreads();
    int node = b * 1024 + t;
    if (node < N) {
        int d = hist[t];
        norm[node] = 1.0f / (float)(d > 1 ? d : 1);
    }
}

// GEMM1: outb[M,128](bf16) = (feat[M,256](fp32->bf16 in-reg) @ W[256,128]) * norm
// All 128 cols per block (W frags for both halves in regs); A read ONCE.
// Transposed-operand MFMA: lane's 4 acc regs = 4 consecutive output cols.
__global__ __launch_bounds__(256)
void k_gemm1(const float* __restrict__ A, int M,
             const float* __restrict__ Wa, const float* __restrict__ Wb, int ldw,
             const float* __restrict__ norm, unsigned short* __restrict__ outb) {
    const int w = threadIdx.x >> 6;
    const int lane = threadIdx.x & 63;
    const int quad = lane >> 4;
    const int l16 = lane & 15;
    const int cl = w * 16 + l16;

    short8 bw[2][8];
#pragma unroll
    for (int hf = 0; hf < 2; ++hf) {
        const float* Wp = hf ? Wb : Wa;
#pragma unroll
        for (int ks = 0; ks < 8; ++ks) {
            union { short8 v; unsigned short u[8]; } c;
#pragma unroll
            for (int j = 0; j < 8; ++j)
                c.u[j] = f2bf(Wp[(size_t)(ks * 32 + quad * 8 + j) * ldw + cl]);
            bw[hf][ks] = c.v;
        }
    }

    const int colbase = w * 16 + quad * 4;

    for (int r0 = blockIdx.x * 64; r0 < M; r0 += gridDim.x * 64) {
        const float* ap[4];
        int rows[4];
#pragma unroll
        for (int m = 0; m < 4; ++m) {
            int row = r0 + m * 16 + l16;
            rows[m] = row;
            int lr = row < M ? row : M - 1;
            ap[m] = A + (size_t)lr * 256 + quad * 8;
        }
        f32x4 acc[4][2];
#pragma unroll
        for (int m = 0; m < 4; ++m) {
            acc[m][0] = (f32x4){0.f, 0.f, 0.f, 0.f};
            acc[m][1] = (f32x4){0.f, 0.f, 0.f, 0.f};
        }
#pragma unroll
        for (int ks = 0; ks < 8; ++ks) {
#pragma unroll
            for (int m = 0; m < 4; ++m) {
                float4 x = *(const float4*)(ap[m] + ks * 32);
                float4 y = *(const float4*)(ap[m] + ks * 32 + 4);
                union { short8 v; unsigned short u[8]; } c;
                c.u[0] = f2bf(x.x); c.u[1] = f2bf(x.y);
                c.u[2] = f2bf(x.z); c.u[3] = f2bf(x.w);
                c.u[4] = f2bf(y.x); c.u[5] = f2bf(y.y);
                c.u[6] = f2bf(y.z); c.u[7] = f2bf(y.w);
                acc[m][0] = __builtin_amdgcn_mfma_f32_16x16x32_bf16(bw[0][ks], c.v, acc[m][0], 0, 0, 0);
                acc[m][1] = __builtin_amdgcn_mfma_f32_16x16x32_bf16(bw[1][ks], c.v, acc[m][1], 0, 0, 0);
            }
        }
#pragma unroll
        for (int m = 0; m < 4; ++m) {
            int row = rows[m];
            if (row < M) {
                float nm = norm[row];
                ushort4 o0, o1;
                o0.x = f2bf(acc[m][0][0] * nm); o0.y = f2bf(acc[m][0][1] * nm);
                o0.z = f2bf(acc[m][0][2] * nm); o0.w = f2bf(acc[m][0][3] * nm);
                o1.x = f2bf(acc[m][1][0] * nm); o1.y = f2bf(acc[m][1][1] * nm);
                o1.z = f2bf(acc[m][1][2] * nm); o1.w = f2bf(acc[m][1][3] * nm);
                *(ushort4*)&outb[(size_t)row * 128 + colbase] = o0;
                *(ushort4*)&outb[(size_t)row * 128 + 64 + colbase] = o1;
            }
        }
    }
}

// GEMM2: outb[M,128](bf16) = (h[M,128](bf16) @ [Wmu|Wls]) * norm; A read once.
__global__ __launch_bounds__(256)
void k_gemm2(const unsigned short* __restrict__ A, int M,
             const float* __restrict__ Wa, const float* __restrict__ Wb, int ldw,
             const float* __restrict__ norm, unsigned short* __restrict__ outb) {
    const int w = threadIdx.x >> 6;
    const int lane = threadIdx.x & 63;
    const int quad = lane >> 4;
    const int l16 = lane & 15;
    const int cl = w * 16 + l16;

    short8 bw[2][4];
#pragma unroll
    for (int hf = 0; hf < 2; ++hf) {
        const float* Wp = hf ? Wb : Wa;
#pragma unroll
        for (int ks = 0; ks < 4; ++ks) {
            union { short8 v; unsigned short u[8]; } c;
#pragma unroll
            for (int j = 0; j < 8; ++j)
                c.u[j] = f2bf(Wp[(size_t)(ks * 32 + quad * 8 + j) * ldw + cl]);
            bw[hf][ks] = c.v;
        }
    }

    const int colbase = w * 16 + quad * 4;

    for (int r0 = blockIdx.x * 64; r0 < M; r0 += gridDim.x * 64) {
        const unsigned short* ap[4];
        int rows[4];
#pragma unroll
        for (int m = 0; m < 4; ++m) {
            int row = r0 + m * 16 + l16;
            rows[m] = row;
            int lr = row < M ? row : M - 1;
            ap[m] = A + (size_t)lr * 128 + quad * 8;
        }
        f32x4 acc[4][2];
#pragma unroll
        for (int m = 0; m < 4; ++m) {
            acc[m][0] = (f32x4){0.f, 0.f, 0.f, 0.f};
            acc[m][1] = (f32x4){0.f, 0.f, 0.f, 0.f};
        }
#pragma unroll
        for (int ks = 0; ks < 4; ++ks) {
#pragma unroll
            for (int m = 0; m < 4; ++m) {
                short8 af = *(const short8*)(ap[m] + ks * 32);
                acc[m][0] = __builtin_amdgcn_mfma_f32_16x16x32_bf16(bw[0][ks], af, acc[m][0], 0, 0, 0);
                acc[m][1] = __builtin_amdgcn_mfma_f32_16x16x32_bf16(bw[1][ks], af, acc[m][1], 0, 0, 0);
            }
        }
#pragma unroll
        for (int m = 0; m < 4; ++m) {
            int row = rows[m];
            if (row < M) {
                float nm = norm[row];
                ushort4 o0, o1;
                o0.x = f2bf(acc[m][0][0] * nm); o0.y = f2bf(acc[m][0][1] * nm);
                o0.z = f2bf(acc[m][0][2] * nm); o0.w = f2bf(acc[m][0][3] * nm);
                o1.x = f2bf(acc[m][1][0] * nm); o1.y = f2bf(acc[m][1][1] * nm);
                o1.z = f2bf(acc[m][1][2] * nm); o1.w = f2bf(acc[m][1][3] * nm);
                *(ushort4*)&outb[(size_t)row * 128 + colbase] = o0;
                *(ushort4*)&outb[(size_t)row * 128 + 64 + colbase] = o1;
            }
        }
    }
}

// SpMM stage 1: half-wave (32 lanes x ushort4 = 256B bf16 row) per node.
__global__ __launch_bounds__(256)
void k_spmm_relu(const int* __restrict__ row_off, const int* __restrict__ col,
                 const unsigned short* __restrict__ hxb, const float* __restrict__ bias,
                 unsigned short* __restrict__ hb, int N) {
    int g = (blockIdx.x * blockDim.x + threadIdx.x) >> 5;
    int l = threadIdx.x & 31;
    if (g >= N) return;
    int e0 = row_off[g], e1 = row_off[g + 1];
    const ushort4* base = (const ushort4*)hxb;
    float4 acc = make_float4(0.f, 0.f, 0.f, 0.f);
    int e = e0;
    for (; e + 1 < e1; e += 2) {
        ushort4 a = base[(size_t)col[e] * 32 + l];
        ushort4 b = base[(size_t)col[e + 1] * 32 + l];
        acc.x += b2f(a.x) + b2f(b.x);
        acc.y += b2f(a.y) + b2f(b.y);
        acc.z += b2f(a.z) + b2f(b.z);
        acc.w += b2f(a.w) + b2f(b.w);
    }
    if (e < e1) {
        ushort4 a = base[(size_t)col[e] * 32 + l];
        acc.x += b2f(a.x); acc.y += b2f(a.y); acc.z += b2f(a.z); acc.w += b2f(a.w);
    }
    float4 bi = ((const float4*)bias)[l];
    ushort4 r;
    r.x = f2bf(fmaxf(acc.x + bi.x, 0.f));
    r.y = f2bf(fmaxf(acc.y + bi.y, 0.f));
    r.z = f2bf(fmaxf(acc.z + bi.z, 0.f));
    r.w = f2bf(fmaxf(acc.w + bi.w, 0.f));
    ((ushort4*)hb)[(size_t)g * 32 + l] = r;
}

// SpMM stage 2 + reparameterization. Lane l<16: mu cols 4l..4l+3; lane l+16: ls.
__global__ __launch_bounds__(256)
void k_spmm_out(const int* __restrict__ row_off, const int* __restrict__ col,
                const unsigned short* __restrict__ hcb, const float* __restrict__ bmu,
                const float* __restrict__ bls, const float* __restrict__ noise,
                float* __restrict__ out, int N) {
    int g = (blockIdx.x * blockDim.x + threadIdx.x) >> 5;
    int l = threadIdx.x & 31;
    if (g >= N) return;
    int e0 = row_off[g], e1 = row_off[g + 1];
    const ushort4* base = (const ushort4*)hcb;
    float4 acc = make_float4(0.f, 0.f, 0.f, 0.f);
    int e = e0;
    for (; e + 1 < e1; e += 2) {
        ushort4 a = base[(size_t)col[e] * 32 + l];
        ushort4 b = base[(size_t)col[e + 1] * 32 + l];
        acc.x += b2f(a.x) + b2f(b.x);
        acc.y += b2f(a.y) + b2f(b.y);
        acc.z += b2f(a.z) + b2f(b.z);
        acc.w += b2f(a.w) + b2f(b.w);
    }
    if (e < e1) {
        ushort4 a = base[(size_t)col[e] * 32 + l];
        acc.x += b2f(a.x); acc.y += b2f(a.y); acc.z += b2f(a.z); acc.w += b2f(a.w);
    }
    int lane64 = threadIdx.x & 63;
    int p = (lane64 + 16) & 63;
    float lx = __shfl(acc.x, p, 64);
    float ly = __shfl(acc.y, p, 64);
    float lz = __shfl(acc.z, p, 64);
    float lw = __shfl(acc.w, p, 64);
    if (l < 16) {
        float4 bm = ((const float4*)bmu)[l];
        float4 bl = ((const float4*)bls)[l];
        float4 nz = ((const float4*)noise)[(size_t)g * 16 + l];
        float4 o;
        o.x = (acc.x + bm.x) + nz.x * expf(lx + bl.x);
        o.y = (acc.y + bm.y) + nz.y * expf(ly + bl.y);
        o.z = (acc.z + bm.z) + nz.z * expf(lz + bl.z);
        o.w = (acc.w + bm.w) + nz.w * expf(lw + bl.w);
        ((float4*)out)[(size_t)g * 16 + l] = o;
    }
}

static inline char* align64(char* p) {
    return (char*)(((uintptr_t)p + 63) & ~(uintptr_t)63);
}

extern "C" void kernel_launch(void* const* d_in, const int* in_sizes, int n_in,
                              void* d_out, int out_size, void* d_ws, size_t ws_size,
                              hipStream_t stream) {
    const float* feat  = (const float*)d_in[0];
    const float* Wsh   = (const float*)d_in[1];
    const float* bsh   = (const float*)d_in[2];
    const float* Wmu   = (const float*)d_in[3];
    const float* bmu   = (const float*)d_in[4];
    const float* Wls   = (const float*)d_in[5];
    const float* bls   = (const float*)d_in[6];
    const float* noise = (const float*)d_in[7];
    const int*   src   = (const int*)d_in[8];
    const int*   dst   = (const int*)d_in[9];
    float* out = (float*)d_out;

    const int N = in_sizes[0] / 256;   // 100000 (<=131072 for 128 coarse buckets)
    const int E = in_sizes[8];         // 1600000
    const int PB = (E + EB - 1) / EB;  // 196

    char* p = (char*)d_ws;
    float* norm   = (float*)p;                  p += (size_t)N * 4;         p = align64(p);
    int* row_off  = (int*)p;                    p += (size_t)(N + 4) * 4;   p = align64(p);
    int* totals   = (int*)p;                    p += 256 * 4;
    int* bbase_d  = (int*)p;                    p += 128 * 4;
    int* bbase_s  = (int*)p;                    p += 128 * 4;               p = align64(p);
    int* bhist    = (int*)p;                    p += (size_t)PB * 256 * 4;  p = align64(p);
    int* boffT    = (int*)p;                    p += (size_t)256 * PB * 4;  p = align64(p);
    int2* parr    = (int2*)p;                   p += (size_t)E * 8;
    int* sarr     = (int*)p;                    p += (size_t)E * 4;
    int* col      = (int*)p;                    p += (size_t)E * 4;         p = align64(p);
    unsigned short* hxb = (unsigned short*)p;                  // N*128 bf16 (hx, then hc)
    unsigned short* hb  = (unsigned short*)d_out;              // N*128 bf16 scratch

    // ---- CSR build (no global atomics except 2K tiny totals adds) ----
    hipMemsetAsync(totals, 0, 256 * sizeof(int), stream);
    k1_hist<<<PB, 256, 0, stream>>>(src, dst, bhist, E);
    kc1_totals<<<8, 256, 0, stream>>>(bhist, totals, PB);
    kc2_scan2<<<1, 256, 0, stream>>>(totals, bbase_d, bbase_s);
    kc3_boff<<<256, 256, 0, stream>>>(bhist, bbase_d, bbase_s, boffT, PB);
    k2_scatter<<<PB, 256, 0, stream>>>(src, dst, boffT, parr, sarr, E, PB);
    k3_dst<<<NBKT, 1024, 0, stream>>>(parr, totals, bbase_d, row_off, col, N, E);
    k3_src<<<NBKT, 1024, 0, stream>>>(sarr, totals + 128, bbase_s, norm, N);

    // ---- dense pipeline (cvt fused into gemm1; A read once per GEMM) ----
    k_gemm1<<<512, 256, 0, stream>>>(feat, N, Wsh, Wsh + 64, 128, norm, hxb);
    k_spmm_relu<<<(N * 32 + 255) / 256, 256, 0, stream>>>(row_off, col, hxb, bsh, hb, N);
    k_gemm2<<<512, 256, 0, stream>>>(hb, N, Wmu, Wls, 64, norm, hxb);
    k_spmm_out<<<(N * 32 + 255) / 256, 256, 0, stream>>>(row_off, col, hxb, bmu, bls, noise, out, N);
}

// Round 6
// 511.453 us; speedup vs baseline: 2.2774x; 1.0346x over previous
//
#include <hip/hip_runtime.h>
#include <math.h>

typedef __attribute__((ext_vector_type(8))) short short8;
typedef __attribute__((ext_vector_type(4))) float f32x4;

// fp32 -> bf16 round-to-nearest-even
__device__ __forceinline__ unsigned short f2bf(float f) {
    unsigned int u = __float_as_uint(f);
    u += 0x7FFF + ((u >> 16) & 1);
    return (unsigned short)(u >> 16);
}
__device__ __forceinline__ float b2f(unsigned short s) {
    return __uint_as_float(((unsigned int)s) << 16);
}

// CSR build via LDS two-level bucket sort, ZERO global atomics.
// COARSE buckets: 128 buckets x 1024 nodes (covers N<=131072).
#define EB 8192        // edges per partition block
#define BSH 10         // node >> 10 = bucket
#define NBKT 128

__global__ __launch_bounds__(256)
void k1_hist(const int* __restrict__ src, const int* __restrict__ dst,
             int* __restrict__ bhist, int E) {
    __shared__ int hist[256];
    int t = threadIdx.x;
    hist[t] = 0;
    __syncthreads();
    int base = blockIdx.x * EB;
    int end = min(base + EB, E);
    for (int e = base + 4 * t; e < end; e += 1024) {
        if (e + 3 < end) {
            int4 d4 = *(const int4*)&dst[e];
            int4 s4 = *(const int4*)&src[e];
            atomicAdd(&hist[d4.x >> BSH], 1);
            atomicAdd(&hist[d4.y >> BSH], 1);
            atomicAdd(&hist[d4.z >> BSH], 1);
            atomicAdd(&hist[d4.w >> BSH], 1);
            atomicAdd(&hist[128 + (s4.x >> BSH)], 1);
            atomicAdd(&hist[128 + (s4.y >> BSH)], 1);
            atomicAdd(&hist[128 + (s4.z >> BSH)], 1);
            atomicAdd(&hist[128 + (s4.w >> BSH)], 1);
        } else {
            for (int q = e; q < end; ++q) {
                atomicAdd(&hist[dst[q] >> BSH], 1);
                atomicAdd(&hist[128 + (src[q] >> BSH)], 1);
            }
        }
    }
    __syncthreads();
    bhist[(size_t)blockIdx.x * 256 + t] = hist[t];
}

__global__ __launch_bounds__(256)
void kc1_totals(const int* __restrict__ bhist, int* __restrict__ totals, int PB) {
    int t = threadIdx.x;
    int slice = (PB + 7) / 8;
    int b0 = blockIdx.x * slice;
    int b1 = min(b0 + slice, PB);
    int s = 0;
    for (int blk = b0; blk < b1; ++blk) s += bhist[(size_t)blk * 256 + t];
    if (s) atomicAdd(&totals[t], s);
}

__global__ __launch_bounds__(256)
void kc2_scan2(const int* __restrict__ totals, int* __restrict__ bbase_d,
               int* __restrict__ bbase_s) {
    __shared__ int s[256];
    int t = threadIdx.x;
    int v = totals[t];
    s[t] = v;
    __syncthreads();
    for (int off = 1; off < 128; off <<= 1) {
        int u = ((t & 127) >= off) ? s[t - off] : 0;
        __syncthreads();
        s[t] += u;
        __syncthreads();
    }
    int excl = s[t] - v;
    if (t < 128) bbase_d[t] = excl;
    else bbase_s[t - 128] = excl;
}

__global__ __launch_bounds__(256)
void kc3_boff(const int* __restrict__ bhist, const int* __restrict__ bbase_d,
              const int* __restrict__ bbase_s, int* __restrict__ boffT, int PB) {
    __shared__ int sums[256];
    int b = blockIdx.x;  // 0..255
    int t = threadIdx.x;
    int v = (t < PB) ? bhist[(size_t)t * 256 + b] : 0;
    sums[t] = v;
    __syncthreads();
    for (int off = 1; off < 256; off <<= 1) {
        int u = (t >= off) ? sums[t - off] : 0;
        __syncthreads();
        sums[t] += u;
        __syncthreads();
    }
    int base = (b < 128) ? bbase_d[b] : bbase_s[b - 128];
    if (t < PB) boffT[(size_t)b * PB + t] = base + sums[t] - v;
}

__global__ __launch_bounds__(256)
void k2_scatter(const int* __restrict__ src, const int* __restrict__ dst,
                const int* __restrict__ boffT, int2* __restrict__ parr,
                int* __restrict__ sarr, int E, int PB) {
    __shared__ int cnt[256];
    int t = threadIdx.x;
    int blk = blockIdx.x;
    cnt[t] = boffT[(size_t)t * PB + blk];
    __syncthreads();
    int base = blk * EB;
    int end = min(base + EB, E);
    for (int e = base + 4 * t; e < end; e += 1024) {
        if (e + 3 < end) {
            int4 s4 = *(const int4*)&src[e];
            int4 d4 = *(const int4*)&dst[e];
            int p0 = atomicAdd(&cnt[d4.x >> BSH], 1); parr[p0] = make_int2(s4.x, d4.x);
            int p1 = atomicAdd(&cnt[d4.y >> BSH], 1); parr[p1] = make_int2(s4.y, d4.y);
            int p2 = atomicAdd(&cnt[d4.z >> BSH], 1); parr[p2] = make_int2(s4.z, d4.z);
            int p3 = atomicAdd(&cnt[d4.w >> BSH], 1); parr[p3] = make_int2(s4.w, d4.w);
            int q0 = atomicAdd(&cnt[128 + (s4.x >> BSH)], 1); sarr[q0] = s4.x;
            int q1 = atomicAdd(&cnt[128 + (s4.y >> BSH)], 1); sarr[q1] = s4.y;
            int q2 = atomicAdd(&cnt[128 + (s4.z >> BSH)], 1); sarr[q2] = s4.z;
            int q3 = atomicAdd(&cnt[128 + (s4.w >> BSH)], 1); sarr[q3] = s4.w;
        } else {
            for (int q = e; q < end; ++q) {
                int sv = src[q], dv = dst[q];
                int pd = atomicAdd(&cnt[dv >> BSH], 1);
                parr[pd] = make_int2(sv, dv);
                int ps = atomicAdd(&cnt[128 + (sv >> BSH)], 1);
                sarr[ps] = sv;
            }
        }
    }
}

__global__ __launch_bounds__(1024)
void k3_dst(const int2* __restrict__ parr, const int* __restrict__ totals,
            const int* __restrict__ bbase_d, int* __restrict__ row_off,
            int* __restrict__ col, int N, int E) {
    __shared__ int hist[1024], sc[1024];
    int b = blockIdx.x, t = threadIdx.x;
    if (b == 0 && t == 0) row_off[N] = E;
    int ne = totals[b];
    int ebase = bbase_d[b];
    hist[t] = 0;
    __syncthreads();
    for (int i = t; i < ne; i += 1024)
        atomicAdd(&hist[parr[ebase + i].y & 1023], 1);
    __syncthreads();
    int h = hist[t];
    sc[t] = h;
    __syncthreads();
    for (int off = 1; off < 1024; off <<= 1) {
        int u = (t >= off) ? sc[t - off] : 0;
        __syncthreads();
        sc[t] += u;
        __syncthreads();
    }
    int excl = sc[t] - h;
    int node = b * 1024 + t;
    if (node < N) row_off[node] = ebase + excl;
    hist[t] = ebase + excl;  // reuse as scatter counters
    __syncthreads();
    for (int i = t; i < ne; i += 1024) {
        int2 pr = parr[ebase + i];
        int slot = atomicAdd(&hist[pr.y & 1023], 1);
        col[slot] = pr.x;
    }
}

__global__ __launch_bounds__(1024)
void k3_src(const int* __restrict__ sarr, const int* __restrict__ totals_s,
            const int* __restrict__ bbase_s, float* __restrict__ norm, int N) {
    __shared__ int hist[1024];
    int b = blockIdx.x, t = threadIdx.x;
    int ne = totals_s[b];
    int sb = bbase_s[b];
    hist[t] = 0;
    __syncthreads();
    for (int i = t; i < ne; i += 1024)
        atomicAdd(&hist[sarr[sb + i] & 1023], 1);
    __syncthreads();
    int node = b * 1024 + t;
    if (node < N) {
        int d = hist[t];
        norm[node] = 1.0f / (float)(d > 1 ? d : 1);
    }
}

// GEMM1: outb[M,128](bf16) = (feat[M,256](fp32->bf16 in-reg) @ W[256,128]) * norm
// One 64-row tile per block (grid = ceil(M/64)): R5's 512-block launch capped
// occupancy at 2 blocks/CU and was latency-bound (VALUBusy 10%, occ 18%).
__global__ __launch_bounds__(256)
void k_gemm1(const float* __restrict__ A, int M,
             const float* __restrict__ Wa, const float* __restrict__ Wb, int ldw,
             const float* __restrict__ norm, unsigned short* __restrict__ outb) {
    const int w = threadIdx.x >> 6;
    const int lane = threadIdx.x & 63;
    const int quad = lane >> 4;
    const int l16 = lane & 15;
    const int cl = w * 16 + l16;

    short8 bw[2][8];
#pragma unroll
    for (int hf = 0; hf < 2; ++hf) {
        const float* Wp = hf ? Wb : Wa;
#pragma unroll
        for (int ks = 0; ks < 8; ++ks) {
            union { short8 v; unsigned short u[8]; } c;
#pragma unroll
            for (int j = 0; j < 8; ++j)
                c.u[j] = f2bf(Wp[(size_t)(ks * 32 + quad * 8 + j) * ldw + cl]);
            bw[hf][ks] = c.v;
        }
    }

    const int colbase = w * 16 + quad * 4;
    const int r0 = blockIdx.x * 64;

    const float* ap[4];
    int rows[4];
#pragma unroll
    for (int m = 0; m < 4; ++m) {
        int row = r0 + m * 16 + l16;
        rows[m] = row;
        int lr = row < M ? row : M - 1;
        ap[m] = A + (size_t)lr * 256 + quad * 8;
    }
    f32x4 acc[4][2];
#pragma unroll
    for (int m = 0; m < 4; ++m) {
        acc[m][0] = (f32x4){0.f, 0.f, 0.f, 0.f};
        acc[m][1] = (f32x4){0.f, 0.f, 0.f, 0.f};
    }
#pragma unroll
    for (int ks = 0; ks < 8; ++ks) {
#pragma unroll
        for (int m = 0; m < 4; ++m) {
            float4 x = *(const float4*)(ap[m] + ks * 32);
            float4 y = *(const float4*)(ap[m] + ks * 32 + 4);
            union { short8 v; unsigned short u[8]; } c;
            c.u[0] = f2bf(x.x); c.u[1] = f2bf(x.y);
            c.u[2] = f2bf(x.z); c.u[3] = f2bf(x.w);
            c.u[4] = f2bf(y.x); c.u[5] = f2bf(y.y);
            c.u[6] = f2bf(y.z); c.u[7] = f2bf(y.w);
            acc[m][0] = __builtin_amdgcn_mfma_f32_16x16x32_bf16(bw[0][ks], c.v, acc[m][0], 0, 0, 0);
            acc[m][1] = __builtin_amdgcn_mfma_f32_16x16x32_bf16(bw[1][ks], c.v, acc[m][1], 0, 0, 0);
        }
    }
#pragma unroll
    for (int m = 0; m < 4; ++m) {
        int row = rows[m];
        if (row < M) {
            float nm = norm[row];
            ushort4 o0, o1;
            o0.x = f2bf(acc[m][0][0] * nm); o0.y = f2bf(acc[m][0][1] * nm);
            o0.z = f2bf(acc[m][0][2] * nm); o0.w = f2bf(acc[m][0][3] * nm);
            o1.x = f2bf(acc[m][1][0] * nm); o1.y = f2bf(acc[m][1][1] * nm);
            o1.z = f2bf(acc[m][1][2] * nm); o1.w = f2bf(acc[m][1][3] * nm);
            *(ushort4*)&outb[(size_t)row * 128 + colbase] = o0;
            *(ushort4*)&outb[(size_t)row * 128 + 64 + colbase] = o1;
        }
    }
}

// GEMM2: outb[M,128](bf16) = (h[M,128](bf16) @ [Wmu|Wls]) * norm; one tile/block.
__global__ __launch_bounds__(256)
void k_gemm2(const unsigned short* __restrict__ A, int M,
             const float* __restrict__ Wa, const float* __restrict__ Wb, int ldw,
             const float* __restrict__ norm, unsigned short* __restrict__ outb) {
    const int w = threadIdx.x >> 6;
    const int lane = threadIdx.x & 63;
    const int quad = lane >> 4;
    const int l16 = lane & 15;
    const int cl = w * 16 + l16;

    short8 bw[2][4];
#pragma unroll
    for (int hf = 0; hf < 2; ++hf) {
        const float* Wp = hf ? Wb : Wa;
#pragma unroll
        for (int ks = 0; ks < 4; ++ks) {
            union { short8 v; unsigned short u[8]; } c;
#pragma unroll
            for (int j = 0; j < 8; ++j)
                c.u[j] = f2bf(Wp[(size_t)(ks * 32 + quad * 8 + j) * ldw + cl]);
            bw[hf][ks] = c.v;
        }
    }

    const int colbase = w * 16 + quad * 4;
    const int r0 = blockIdx.x * 64;

    const unsigned short* ap[4];
    int rows[4];
#pragma unroll
    for (int m = 0; m < 4; ++m) {
        int row = r0 + m * 16 + l16;
        rows[m] = row;
        int lr = row < M ? row : M - 1;
        ap[m] = A + (size_t)lr * 128 + quad * 8;
    }
    f32x4 acc[4][2];
#pragma unroll
    for (int m = 0; m < 4; ++m) {
        acc[m][0] = (f32x4){0.f, 0.f, 0.f, 0.f};
        acc[m][1] = (f32x4){0.f, 0.f, 0.f, 0.f};
    }
#pragma unroll
    for (int ks = 0; ks < 4; ++ks) {
#pragma unroll
        for (int m = 0; m < 4; ++m) {
            short8 af = *(const short8*)(ap[m] + ks * 32);
            acc[m][0] = __builtin_amdgcn_mfma_f32_16x16x32_bf16(bw[0][ks], af, acc[m][0], 0, 0, 0);
            acc[m][1] = __builtin_amdgcn_mfma_f32_16x16x32_bf16(bw[1][ks], af, acc[m][1], 0, 0, 0);
        }
    }
#pragma unroll
    for (int m = 0; m < 4; ++m) {
        int row = rows[m];
        if (row < M) {
            float nm = norm[row];
            ushort4 o0, o1;
            o0.x = f2bf(acc[m][0][0] * nm); o0.y = f2bf(acc[m][0][1] * nm);
            o0.z = f2bf(acc[m][0][2] * nm); o0.w = f2bf(acc[m][0][3] * nm);
            o1.x = f2bf(acc[m][1][0] * nm); o1.y = f2bf(acc[m][1][1] * nm);
            o1.z = f2bf(acc[m][1][2] * nm); o1.w = f2bf(acc[m][1][3] * nm);
            *(ushort4*)&outb[(size_t)row * 128 + colbase] = o0;
            *(ushort4*)&outb[(size_t)row * 128 + 64 + colbase] = o1;
        }
    }
}

// SpMM stage 1: half-wave (32 lanes x ushort4 = 256B bf16 row) per node.
__global__ __launch_bounds__(256)
void k_spmm_relu(const int* __restrict__ row_off, const int* __restrict__ col,
                 const unsigned short* __restrict__ hxb, const float* __restrict__ bias,
                 unsigned short* __restrict__ hb, int N) {
    int g = (blockIdx.x * blockDim.x + threadIdx.x) >> 5;
    int l = threadIdx.x & 31;
    if (g >= N) return;
    int e0 = row_off[g], e1 = row_off[g + 1];
    const ushort4* base = (const ushort4*)hxb;
    float4 acc = make_float4(0.f, 0.f, 0.f, 0.f);
    int e = e0;
    for (; e + 1 < e1; e += 2) {
        ushort4 a = base[(size_t)col[e] * 32 + l];
        ushort4 b = base[(size_t)col[e + 1] * 32 + l];
        acc.x += b2f(a.x) + b2f(b.x);
        acc.y += b2f(a.y) + b2f(b.y);
        acc.z += b2f(a.z) + b2f(b.z);
        acc.w += b2f(a.w) + b2f(b.w);
    }
    if (e < e1) {
        ushort4 a = base[(size_t)col[e] * 32 + l];
        acc.x += b2f(a.x); acc.y += b2f(a.y); acc.z += b2f(a.z); acc.w += b2f(a.w);
    }
    float4 bi = ((const float4*)bias)[l];
    ushort4 r;
    r.x = f2bf(fmaxf(acc.x + bi.x, 0.f));
    r.y = f2bf(fmaxf(acc.y + bi.y, 0.f));
    r.z = f2bf(fmaxf(acc.z + bi.z, 0.f));
    r.w = f2bf(fmaxf(acc.w + bi.w, 0.f));
    ((ushort4*)hb)[(size_t)g * 32 + l] = r;
}

// SpMM stage 2 + reparameterization. Lane l<16: mu cols 4l..4l+3; lane l+16: ls.
__global__ __launch_bounds__(256)
void k_spmm_out(const int* __restrict__ row_off, const int* __restrict__ col,
                const unsigned short* __restrict__ hcb, const float* __restrict__ bmu,
                const float* __restrict__ bls, const float* __restrict__ noise,
                float* __restrict__ out, int N) {
    int g = (blockIdx.x * blockDim.x + threadIdx.x) >> 5;
    int l = threadIdx.x & 31;
    if (g >= N) return;
    int e0 = row_off[g], e1 = row_off[g + 1];
    const ushort4* base = (const ushort4*)hcb;
    float4 acc = make_float4(0.f, 0.f, 0.f, 0.f);
    int e = e0;
    for (; e + 1 < e1; e += 2) {
        ushort4 a = base[(size_t)col[e] * 32 + l];
        ushort4 b = base[(size_t)col[e + 1] * 32 + l];
        acc.x += b2f(a.x) + b2f(b.x);
        acc.y += b2f(a.y) + b2f(b.y);
        acc.z += b2f(a.z) + b2f(b.z);
        acc.w += b2f(a.w) + b2f(b.w);
    }
    if (e < e1) {
        ushort4 a = base[(size_t)col[e] * 32 + l];
        acc.x += b2f(a.x); acc.y += b2f(a.y); acc.z += b2f(a.z); acc.w += b2f(a.w);
    }
    int lane64 = threadIdx.x & 63;
    int p = (lane64 + 16) & 63;
    float lx = __shfl(acc.x, p, 64);
    float ly = __shfl(acc.y, p, 64);
    float lz = __shfl(acc.z, p, 64);
    float lw = __shfl(acc.w, p, 64);
    if (l < 16) {
        float4 bm = ((const float4*)bmu)[l];
        float4 bl = ((const float4*)bls)[l];
        float4 nz = ((const float4*)noise)[(size_t)g * 16 + l];
        float4 o;
        o.x = (acc.x + bm.x) + nz.x * expf(lx + bl.x);
        o.y = (acc.y + bm.y) + nz.y * expf(ly + bl.y);
        o.z = (acc.z + bm.z) + nz.z * expf(lz + bl.z);
        o.w = (acc.w + bm.w) + nz.w * expf(lw + bl.w);
        ((float4*)out)[(size_t)g * 16 + l] = o;
    }
}

static inline char* align64(char* p) {
    return (char*)(((uintptr_t)p + 63) & ~(uintptr_t)63);
}

extern "C" void kernel_launch(void* const* d_in, const int* in_sizes, int n_in,
                              void* d_out, int out_size, void* d_ws, size_t ws_size,
                              hipStream_t stream) {
    const float* feat  = (const float*)d_in[0];
    const float* Wsh   = (const float*)d_in[1];
    const float* bsh   = (const float*)d_in[2];
    const float* Wmu   = (const float*)d_in[3];
    const float* bmu   = (const float*)d_in[4];
    const float* Wls   = (const float*)d_in[5];
    const float* bls   = (const float*)d_in[6];
    const float* noise = (const float*)d_in[7];
    const int*   src   = (const int*)d_in[8];
    const int*   dst   = (const int*)d_in[9];
    float* out = (float*)d_out;

    const int N = in_sizes[0] / 256;   // 100000 (<=131072 for 128 coarse buckets)
    const int E = in_sizes[8];         // 1600000
    const int PB = (E + EB - 1) / EB;  // 196

    char* p = (char*)d_ws;
    float* norm   = (float*)p;                  p += (size_t)N * 4;         p = align64(p);
    int* row_off  = (int*)p;                    p += (size_t)(N + 4) * 4;   p = align64(p);
    int* totals   = (int*)p;                    p += 256 * 4;
    int* bbase_d  = (int*)p;                    p += 128 * 4;
    int* bbase_s  = (int*)p;                    p += 128 * 4;               p = align64(p);
    int* bhist    = (int*)p;                    p += (size_t)PB * 256 * 4;  p = align64(p);
    int* boffT    = (int*)p;                    p += (size_t)256 * PB * 4;  p = align64(p);
    int2* parr    = (int2*)p;                   p += (size_t)E * 8;
    int* sarr     = (int*)p;                    p += (size_t)E * 4;
    int* col      = (int*)p;                    p += (size_t)E * 4;         p = align64(p);
    unsigned short* hxb = (unsigned short*)p;                  // N*128 bf16 (hx, then hc)
    unsigned short* hb  = (unsigned short*)d_out;              // N*128 bf16 scratch

    // ---- CSR build (no global atomics except 256 tiny totals adds) ----
    hipMemsetAsync(totals, 0, 256 * sizeof(int), stream);
    k1_hist<<<PB, 256, 0, stream>>>(src, dst, bhist, E);
    kc1_totals<<<8, 256, 0, stream>>>(bhist, totals, PB);
    kc2_scan2<<<1, 256, 0, stream>>>(totals, bbase_d, bbase_s);
    kc3_boff<<<256, 256, 0, stream>>>(bhist, bbase_d, bbase_s, boffT, PB);
    k2_scatter<<<PB, 256, 0, stream>>>(src, dst, boffT, parr, sarr, E, PB);
    k3_dst<<<NBKT, 1024, 0, stream>>>(parr, totals, bbase_d, row_off, col, N, E);
    k3_src<<<NBKT, 1024, 0, stream>>>(sarr, totals + 128, bbase_s, norm, N);

    // ---- dense pipeline (one 64-row tile per block for full occupancy) ----
    int gtiles = (N + 63) / 64;  // 1563
    k_gemm1<<<gtiles, 256, 0, stream>>>(feat, N, Wsh, Wsh + 64, 128, norm, hxb);
    k_spmm_relu<<<(N * 32 + 255) / 256, 256, 0, stream>>>(row_off, col, hxb, bsh, hb, N);
    k_gemm2<<<gtiles, 256, 0, stream>>>(hb, N, Wmu, Wls, 64, norm, hxb);
    k_spmm_out<<<(N * 32 + 255) / 256, 256, 0, stream>>>(row_off, col, hxb, bmu, bls, noise, out, N);
}

// Round 7
// 481.334 us; speedup vs baseline: 2.4200x; 1.0626x over previous
//
#include <hip/hip_runtime.h>
#include <hip/hip_bf16.h>
#include <math.h>

typedef __attribute__((ext_vector_type(8))) short short8;
typedef __attribute__((ext_vector_type(4))) float f32x4;

// fp32 -> bf16 round-to-nearest-even (scalar)
__device__ __forceinline__ unsigned short f2bf(float f) {
    unsigned int u = __float_as_uint(f);
    u += 0x7FFF + ((u >> 16) & 1);
    return (unsigned short)(u >> 16);
}
__device__ __forceinline__ float b2f(unsigned short s) {
    return __uint_as_float(((unsigned int)s) << 16);
}
// packed fp32x2 -> bf16x2 RNE (v_cvt_pk_bf16_f32 on gfx950)
__device__ __forceinline__ unsigned int f2bf2(float a, float b) {
    __hip_bfloat162 h = __float22bfloat162_rn(make_float2(a, b));
    return *(unsigned int*)&h;
}

// CSR build via LDS two-level bucket sort, ZERO global atomics.
// COARSE buckets: 128 buckets x 1024 nodes (covers N<=131072).
#define EB 8192        // edges per partition block
#define BSH 10         // node >> 10 = bucket
#define NBKT 128

__global__ __launch_bounds__(256)
void k1_hist(const int* __restrict__ src, const int* __restrict__ dst,
             int* __restrict__ bhist, int E) {
    __shared__ int hist[256];
    int t = threadIdx.x;
    hist[t] = 0;
    __syncthreads();
    int base = blockIdx.x * EB;
    int end = min(base + EB, E);
    for (int e = base + 4 * t; e < end; e += 1024) {
        if (e + 3 < end) {
            int4 d4 = *(const int4*)&dst[e];
            int4 s4 = *(const int4*)&src[e];
            atomicAdd(&hist[d4.x >> BSH], 1);
            atomicAdd(&hist[d4.y >> BSH], 1);
            atomicAdd(&hist[d4.z >> BSH], 1);
            atomicAdd(&hist[d4.w >> BSH], 1);
            atomicAdd(&hist[128 + (s4.x >> BSH)], 1);
            atomicAdd(&hist[128 + (s4.y >> BSH)], 1);
            atomicAdd(&hist[128 + (s4.z >> BSH)], 1);
            atomicAdd(&hist[128 + (s4.w >> BSH)], 1);
        } else {
            for (int q = e; q < end; ++q) {
                atomicAdd(&hist[dst[q] >> BSH], 1);
                atomicAdd(&hist[128 + (src[q] >> BSH)], 1);
            }
        }
    }
    __syncthreads();
    bhist[(size_t)blockIdx.x * 256 + t] = hist[t];
}

__global__ __launch_bounds__(256)
void kc1_totals(const int* __restrict__ bhist, int* __restrict__ totals, int PB) {
    int t = threadIdx.x;
    int slice = (PB + 7) / 8;
    int b0 = blockIdx.x * slice;
    int b1 = min(b0 + slice, PB);
    int s = 0;
    for (int blk = b0; blk < b1; ++blk) s += bhist[(size_t)blk * 256 + t];
    if (s) atomicAdd(&totals[t], s);
}

__global__ __launch_bounds__(256)
void kc2_scan2(const int* __restrict__ totals, int* __restrict__ bbase_d,
               int* __restrict__ bbase_s) {
    __shared__ int s[256];
    int t = threadIdx.x;
    int v = totals[t];
    s[t] = v;
    __syncthreads();
    for (int off = 1; off < 128; off <<= 1) {
        int u = ((t & 127) >= off) ? s[t - off] : 0;
        __syncthreads();
        s[t] += u;
        __syncthreads();
    }
    int excl = s[t] - v;
    if (t < 128) bbase_d[t] = excl;
    else bbase_s[t - 128] = excl;
}

__global__ __launch_bounds__(256)
void kc3_boff(const int* __restrict__ bhist, const int* __restrict__ bbase_d,
              const int* __restrict__ bbase_s, int* __restrict__ boffT, int PB) {
    __shared__ int sums[256];
    int b = blockIdx.x;  // 0..255
    int t = threadIdx.x;
    int v = (t < PB) ? bhist[(size_t)t * 256 + b] : 0;
    sums[t] = v;
    __syncthreads();
    for (int off = 1; off < 256; off <<= 1) {
        int u = (t >= off) ? sums[t - off] : 0;
        __syncthreads();
        sums[t] += u;
        __syncthreads();
    }
    int base = (b < 128) ? bbase_d[b] : bbase_s[b - 128];
    if (t < PB) boffT[(size_t)b * PB + t] = base + sums[t] - v;
}

__global__ __launch_bounds__(256)
void k2_scatter(const int* __restrict__ src, const int* __restrict__ dst,
                const int* __restrict__ boffT, int2* __restrict__ parr,
                int* __restrict__ sarr, int E, int PB) {
    __shared__ int cnt[256];
    int t = threadIdx.x;
    int blk = blockIdx.x;
    cnt[t] = boffT[(size_t)t * PB + blk];
    __syncthreads();
    int base = blk * EB;
    int end = min(base + EB, E);
    for (int e = base + 4 * t; e < end; e += 1024) {
        if (e + 3 < end) {
            int4 s4 = *(const int4*)&src[e];
            int4 d4 = *(const int4*)&dst[e];
            int p0 = atomicAdd(&cnt[d4.x >> BSH], 1); parr[p0] = make_int2(s4.x, d4.x);
            int p1 = atomicAdd(&cnt[d4.y >> BSH], 1); parr[p1] = make_int2(s4.y, d4.y);
            int p2 = atomicAdd(&cnt[d4.z >> BSH], 1); parr[p2] = make_int2(s4.z, d4.z);
            int p3 = atomicAdd(&cnt[d4.w >> BSH], 1); parr[p3] = make_int2(s4.w, d4.w);
            int q0 = atomicAdd(&cnt[128 + (s4.x >> BSH)], 1); sarr[q0] = s4.x;
            int q1 = atomicAdd(&cnt[128 + (s4.y >> BSH)], 1); sarr[q1] = s4.y;
            int q2 = atomicAdd(&cnt[128 + (s4.z >> BSH)], 1); sarr[q2] = s4.z;
            int q3 = atomicAdd(&cnt[128 + (s4.w >> BSH)], 1); sarr[q3] = s4.w;
        } else {
            for (int q = e; q < end; ++q) {
                int sv = src[q], dv = dst[q];
                int pd = atomicAdd(&cnt[dv >> BSH], 1);
                parr[pd] = make_int2(sv, dv);
                int ps = atomicAdd(&cnt[128 + (sv >> BSH)], 1);
                sarr[ps] = sv;
            }
        }
    }
}

__global__ __launch_bounds__(1024)
void k3_dst(const int2* __restrict__ parr, const int* __restrict__ totals,
            const int* __restrict__ bbase_d, int* __restrict__ row_off,
            int* __restrict__ col, int N, int E) {
    __shared__ int hist[1024], sc[1024];
    int b = blockIdx.x, t = threadIdx.x;
    if (b == 0 && t == 0) row_off[N] = E;
    int ne = totals[b];
    int ebase = bbase_d[b];
    hist[t] = 0;
    __syncthreads();
    for (int i = t; i < ne; i += 1024)
        atomicAdd(&hist[parr[ebase + i].y & 1023], 1);
    __syncthreads();
    int h = hist[t];
    sc[t] = h;
    __syncthreads();
    for (int off = 1; off < 1024; off <<= 1) {
        int u = (t >= off) ? sc[t - off] : 0;
        __syncthreads();
        sc[t] += u;
        __syncthreads();
    }
    int excl = sc[t] - h;
    int node = b * 1024 + t;
    if (node < N) row_off[node] = ebase + excl;
    hist[t] = ebase + excl;  // reuse as scatter counters
    __syncthreads();
    for (int i = t; i < ne; i += 1024) {
        int2 pr = parr[ebase + i];
        int slot = atomicAdd(&hist[pr.y & 1023], 1);
        col[slot] = pr.x;
    }
}

__global__ __launch_bounds__(1024)
void k3_src(const int* __restrict__ sarr, const int* __restrict__ totals_s,
            const int* __restrict__ bbase_s, float* __restrict__ norm, int N) {
    __shared__ int hist[1024];
    int b = blockIdx.x, t = threadIdx.x;
    int ne = totals_s[b];
    int sb = bbase_s[b];
    hist[t] = 0;
    __syncthreads();
    for (int i = t; i < ne; i += 1024)
        atomicAdd(&hist[sarr[sb + i] & 1023], 1);
    __syncthreads();
    int node = b * 1024 + t;
    if (node < N) {
        int d = hist[t];
        norm[node] = 1.0f / (float)(d > 1 ? d : 1);
    }
}

// Pre-transpose + pre-convert weights to bf16, fragment-contiguous:
//   W1T[n][k] = bf16(Wsh[k][n])   n<128, k<256
//   W2T[n][k] = bf16(n<64 ? Wmu[k][n] : Wls[k][n-64])   n<128, k<128
// Kills the per-block scalar W prologue in the GEMMs (was 128 scalar
// loads + cvts per thread per block — rivaled the MFMA work itself).
__global__ __launch_bounds__(256)
void k_wprep(const float* __restrict__ Wsh, const float* __restrict__ Wmu,
             const float* __restrict__ Wls, unsigned short* __restrict__ W1T,
             unsigned short* __restrict__ W2T) {
    int b = blockIdx.x, t = threadIdx.x;
    if (b < 128) {
        W1T[(size_t)b * 256 + t] = f2bf(Wsh[(size_t)t * 128 + b]);
    } else {
        int n = b - 128;
        if (t < 128) {
            float v = (n < 64) ? Wmu[(size_t)t * 64 + n]
                               : Wls[(size_t)t * 64 + (n - 64)];
            W2T[(size_t)n * 128 + t] = f2bf(v);
        }
    }
}

// GEMM1: outb[M,128](bf16) = (feat[M,256](fp32->bf16 in-reg) @ W) * norm
// One 64-row tile per block. W fragments: 16 short8 vector loads from W1T.
// Transposed-operand MFMA: lane's 4 acc regs = 4 consecutive output cols.
__global__ __launch_bounds__(256)
void k_gemm1(const float* __restrict__ A, int M,
             const unsigned short* __restrict__ W1T,
             const float* __restrict__ norm, unsigned short* __restrict__ outb) {
    const int w = threadIdx.x >> 6;
    const int lane = threadIdx.x & 63;
    const int quad = lane >> 4;
    const int l16 = lane & 15;
    const int cl = w * 16 + l16;

    short8 bw[2][8];
#pragma unroll
    for (int hf = 0; hf < 2; ++hf) {
        const unsigned short* wp = W1T + (size_t)(hf * 64 + cl) * 256 + quad * 8;
#pragma unroll
        for (int ks = 0; ks < 8; ++ks)
            bw[hf][ks] = *(const short8*)(wp + ks * 32);
    }

    const int colbase = w * 16 + quad * 4;
    const int r0 = blockIdx.x * 64;

    const float* ap[4];
    int rows[4];
#pragma unroll
    for (int m = 0; m < 4; ++m) {
        int row = r0 + m * 16 + l16;
        rows[m] = row;
        int lr = row < M ? row : M - 1;
        ap[m] = A + (size_t)lr * 256 + quad * 8;
    }
    f32x4 acc[4][2];
#pragma unroll
    for (int m = 0; m < 4; ++m) {
        acc[m][0] = (f32x4){0.f, 0.f, 0.f, 0.f};
        acc[m][1] = (f32x4){0.f, 0.f, 0.f, 0.f};
    }
#pragma unroll
    for (int ks = 0; ks < 8; ++ks) {
#pragma unroll
        for (int m = 0; m < 4; ++m) {
            float4 x = *(const float4*)(ap[m] + ks * 32);
            float4 y = *(const float4*)(ap[m] + ks * 32 + 4);
            union { short8 v; unsigned int u[4]; } c;
            c.u[0] = f2bf2(x.x, x.y);
            c.u[1] = f2bf2(x.z, x.w);
            c.u[2] = f2bf2(y.x, y.y);
            c.u[3] = f2bf2(y.z, y.w);
            acc[m][0] = __builtin_amdgcn_mfma_f32_16x16x32_bf16(bw[0][ks], c.v, acc[m][0], 0, 0, 0);
            acc[m][1] = __builtin_amdgcn_mfma_f32_16x16x32_bf16(bw[1][ks], c.v, acc[m][1], 0, 0, 0);
        }
    }
#pragma unroll
    for (int m = 0; m < 4; ++m) {
        int row = rows[m];
        if (row < M) {
            float nm = norm[row];
            ushort4 o0, o1;
            o0.x = f2bf(acc[m][0][0] * nm); o0.y = f2bf(acc[m][0][1] * nm);
            o0.z = f2bf(acc[m][0][2] * nm); o0.w = f2bf(acc[m][0][3] * nm);
            o1.x = f2bf(acc[m][1][0] * nm); o1.y = f2bf(acc[m][1][1] * nm);
            o1.z = f2bf(acc[m][1][2] * nm); o1.w = f2bf(acc[m][1][3] * nm);
            *(ushort4*)&outb[(size_t)row * 128 + colbase] = o0;
            *(ushort4*)&outb[(size_t)row * 128 + 64 + colbase] = o1;
        }
    }
}

// GEMM2: outb[M,128](bf16) = (h[M,128](bf16) @ [Wmu|Wls]) * norm.
__global__ __launch_bounds__(256)
void k_gemm2(const unsigned short* __restrict__ A, int M,
             const unsigned short* __restrict__ W2T,
             const float* __restrict__ norm, unsigned short* __restrict__ outb) {
    const int w = threadIdx.x >> 6;
    const int lane = threadIdx.x & 63;
    const int quad = lane >> 4;
    const int l16 = lane & 15;
    const int cl = w * 16 + l16;

    short8 bw[2][4];
#pragma unroll
    for (int hf = 0; hf < 2; ++hf) {
        const unsigned short* wp = W2T + (size_t)(hf * 64 + cl) * 128 + quad * 8;
#pragma unroll
        for (int ks = 0; ks < 4; ++ks)
            bw[hf][ks] = *(const short8*)(wp + ks * 32);
    }

    const int colbase = w * 16 + quad * 4;
    const int r0 = blockIdx.x * 64;

    const unsigned short* ap[4];
    int rows[4];
#pragma unroll
    for (int m = 0; m < 4; ++m) {
        int row = r0 + m * 16 + l16;
        rows[m] = row;
        int lr = row < M ? row : M - 1;
        ap[m] = A + (size_t)lr * 128 + quad * 8;
    }
    f32x4 acc[4][2];
#pragma unroll
    for (int m = 0; m < 4; ++m) {
        acc[m][0] = (f32x4){0.f, 0.f, 0.f, 0.f};
        acc[m][1] = (f32x4){0.f, 0.f, 0.f, 0.f};
    }
#pragma unroll
    for (int ks = 0; ks < 4; ++ks) {
#pragma unroll
        for (int m = 0; m < 4; ++m) {
            short8 af = *(const short8*)(ap[m] + ks * 32);
            acc[m][0] = __builtin_amdgcn_mfma_f32_16x16x32_bf16(bw[0][ks], af, acc[m][0], 0, 0, 0);
            acc[m][1] = __builtin_amdgcn_mfma_f32_16x16x32_bf16(bw[1][ks], af, acc[m][1], 0, 0, 0);
        }
    }
#pragma unroll
    for (int m = 0; m < 4; ++m) {
        int row = rows[m];
        if (row < M) {
            float nm = norm[row];
            ushort4 o0, o1;
            o0.x = f2bf(acc[m][0][0] * nm); o0.y = f2bf(acc[m][0][1] * nm);
            o0.z = f2bf(acc[m][0][2] * nm); o0.w = f2bf(acc[m][0][3] * nm);
            o1.x = f2bf(acc[m][1][0] * nm); o1.y = f2bf(acc[m][1][1] * nm);
            o1.z = f2bf(acc[m][1][2] * nm); o1.w = f2bf(acc[m][1][3] * nm);
            *(ushort4*)&outb[(size_t)row * 128 + colbase] = o0;
            *(ushort4*)&outb[(size_t)row * 128 + 64 + colbase] = o1;
        }
    }
}

// SpMM stage 1: half-wave (32 lanes x ushort4 = 256B bf16 row) per node.
// 4-wide unroll: 4 independent row gathers in flight per iteration.
__global__ __launch_bounds__(256)
void k_spmm_relu(const int* __restrict__ row_off, const int* __restrict__ col,
                 const unsigned short* __restrict__ hxb, const float* __restrict__ bias,
                 unsigned short* __restrict__ hb, int N) {
    int g = (blockIdx.x * blockDim.x + threadIdx.x) >> 5;
    int l = threadIdx.x & 31;
    if (g >= N) return;
    int e0 = row_off[g], e1 = row_off[g + 1];
    const ushort4* base = (const ushort4*)hxb;
    float4 acc = make_float4(0.f, 0.f, 0.f, 0.f);
    int e = e0;
    for (; e + 3 < e1; e += 4) {
        int s0 = col[e], s1 = col[e + 1], s2 = col[e + 2], s3 = col[e + 3];
        ushort4 a = base[(size_t)s0 * 32 + l];
        ushort4 b = base[(size_t)s1 * 32 + l];
        ushort4 c = base[(size_t)s2 * 32 + l];
        ushort4 d = base[(size_t)s3 * 32 + l];
        acc.x += (b2f(a.x) + b2f(b.x)) + (b2f(c.x) + b2f(d.x));
        acc.y += (b2f(a.y) + b2f(b.y)) + (b2f(c.y) + b2f(d.y));
        acc.z += (b2f(a.z) + b2f(b.z)) + (b2f(c.z) + b2f(d.z));
        acc.w += (b2f(a.w) + b2f(b.w)) + (b2f(c.w) + b2f(d.w));
    }
    for (; e < e1; ++e) {
        ushort4 a = base[(size_t)col[e] * 32 + l];
        acc.x += b2f(a.x); acc.y += b2f(a.y); acc.z += b2f(a.z); acc.w += b2f(a.w);
    }
    float4 bi = ((const float4*)bias)[l];
    ushort4 r;
    r.x = f2bf(fmaxf(acc.x + bi.x, 0.f));
    r.y = f2bf(fmaxf(acc.y + bi.y, 0.f));
    r.z = f2bf(fmaxf(acc.z + bi.z, 0.f));
    r.w = f2bf(fmaxf(acc.w + bi.w, 0.f));
    ((ushort4*)hb)[(size_t)g * 32 + l] = r;
}

// SpMM stage 2 + reparameterization. Lane l<16: mu cols 4l..4l+3; lane l+16: ls.
__global__ __launch_bounds__(256)
void k_spmm_out(const int* __restrict__ row_off, const int* __restrict__ col,
                const unsigned short* __restrict__ hcb, const float* __restrict__ bmu,
                const float* __restrict__ bls, const float* __restrict__ noise,
                float* __restrict__ out, int N) {
    int g = (blockIdx.x * blockDim.x + threadIdx.x) >> 5;
    int l = threadIdx.x & 31;
    if (g >= N) return;
    int e0 = row_off[g], e1 = row_off[g + 1];
    const ushort4* base = (const ushort4*)hcb;
    float4 acc = make_float4(0.f, 0.f, 0.f, 0.f);
    int e = e0;
    for (; e + 3 < e1; e += 4) {
        int s0 = col[e], s1 = col[e + 1], s2 = col[e + 2], s3 = col[e + 3];
        ushort4 a = base[(size_t)s0 * 32 + l];
        ushort4 b = base[(size_t)s1 * 32 + l];
        ushort4 c = base[(size_t)s2 * 32 + l];
        ushort4 d = base[(size_t)s3 * 32 + l];
        acc.x += (b2f(a.x) + b2f(b.x)) + (b2f(c.x) + b2f(d.x));
        acc.y += (b2f(a.y) + b2f(b.y)) + (b2f(c.y) + b2f(d.y));
        acc.z += (b2f(a.z) + b2f(b.z)) + (b2f(c.z) + b2f(d.z));
        acc.w += (b2f(a.w) + b2f(b.w)) + (b2f(c.w) + b2f(d.w));
    }
    for (; e < e1; ++e) {
        ushort4 a = base[(size_t)col[e] * 32 + l];
        acc.x += b2f(a.x); acc.y += b2f(a.y); acc.z += b2f(a.z); acc.w += b2f(a.w);
    }
    int lane64 = threadIdx.x & 63;
    int p = (lane64 + 16) & 63;
    float lx = __shfl(acc.x, p, 64);
    float ly = __shfl(acc.y, p, 64);
    float lz = __shfl(acc.z, p, 64);
    float lw = __shfl(acc.w, p, 64);
    if (l < 16) {
        float4 bm = ((const float4*)bmu)[l];
        float4 bl = ((const float4*)bls)[l];
        float4 nz = ((const float4*)noise)[(size_t)g * 16 + l];
        float4 o;
        o.x = (acc.x + bm.x) + nz.x * expf(lx + bl.x);
        o.y = (acc.y + bm.y) + nz.y * expf(ly + bl.y);
        o.z = (acc.z + bm.z) + nz.z * expf(lz + bl.z);
        o.w = (acc.w + bm.w) + nz.w * expf(lw + bl.w);
        ((float4*)out)[(size_t)g * 16 + l] = o;
    }
}

static inline char* align64(char* p) {
    return (char*)(((uintptr_t)p + 63) & ~(uintptr_t)63);
}

extern "C" void kernel_launch(void* const* d_in, const int* in_sizes, int n_in,
                              void* d_out, int out_size, void* d_ws, size_t ws_size,
                              hipStream_t stream) {
    const float* feat  = (const float*)d_in[0];
    const float* Wsh   = (const float*)d_in[1];
    const float* bsh   = (const float*)d_in[2];
    const float* Wmu   = (const float*)d_in[3];
    const float* bmu   = (const float*)d_in[4];
    const float* Wls   = (const float*)d_in[5];
    const float* bls   = (const float*)d_in[6];
    const float* noise = (const float*)d_in[7];
    const int*   src   = (const int*)d_in[8];
    const int*   dst   = (const int*)d_in[9];
    float* out = (float*)d_out;

    const int N = in_sizes[0] / 256;   // 100000 (<=131072 for 128 coarse buckets)
    const int E = in_sizes[8];         // 1600000
    const int PB = (E + EB - 1) / EB;  // 196

    char* p = (char*)d_ws;
    float* norm   = (float*)p;                  p += (size_t)N * 4;         p = align64(p);
    int* row_off  = (int*)p;                    p += (size_t)(N + 4) * 4;   p = align64(p);
    int* totals   = (int*)p;                    p += 256 * 4;
    int* bbase_d  = (int*)p;                    p += 128 * 4;
    int* bbase_s  = (int*)p;                    p += 128 * 4;               p = align64(p);
    unsigned short* W1T = (unsigned short*)p;   p += (size_t)128 * 256 * 2; // 64 KB
    unsigned short* W2T = (unsigned short*)p;   p += (size_t)128 * 128 * 2; // 32 KB
    p = align64(p);
    int* bhist    = (int*)p;                    p += (size_t)PB * 256 * 4;  p = align64(p);
    int* boffT    = (int*)p;                    p += (size_t)256 * PB * 4;  p = align64(p);
    int2* parr    = (int2*)p;                   p += (size_t)E * 8;
    int* sarr     = (int*)p;                    p += (size_t)E * 4;
    int* col      = (int*)p;                    p += (size_t)E * 4;         p = align64(p);
    unsigned short* hxb = (unsigned short*)p;                  // N*128 bf16 (hx, then hc)
    unsigned short* hb  = (unsigned short*)d_out;              // N*128 bf16 scratch

    // ---- CSR build (no global atomics except 256 tiny totals adds) ----
    hipMemsetAsync(totals, 0, 256 * sizeof(int), stream);
    k_wprep<<<256, 256, 0, stream>>>(Wsh, Wmu, Wls, W1T, W2T);
    k1_hist<<<PB, 256, 0, stream>>>(src, dst, bhist, E);
    kc1_totals<<<8, 256, 0, stream>>>(bhist, totals, PB);
    kc2_scan2<<<1, 256, 0, stream>>>(totals, bbase_d, bbase_s);
    kc3_boff<<<256, 256, 0, stream>>>(bhist, bbase_d, bbase_s, boffT, PB);
    k2_scatter<<<PB, 256, 0, stream>>>(src, dst, boffT, parr, sarr, E, PB);
    k3_dst<<<NBKT, 1024, 0, stream>>>(parr, totals, bbase_d, row_off, col, N, E);
    k3_src<<<NBKT, 1024, 0, stream>>>(sarr, totals + 128, bbase_s, norm, N);

    // ---- dense pipeline ----
    int gtiles = (N + 63) / 64;  // 1563
    k_gemm1<<<gtiles, 256, 0, stream>>>(feat, N, W1T, norm, hxb);
    k_spmm_relu<<<(N * 32 + 255) / 256, 256, 0, stream>>>(row_off, col, hxb, bsh, hb, N);
    k_gemm2<<<gtiles, 256, 0, stream>>>(hb, N, W2T, norm, hxb);
    k_spmm_out<<<(N * 32 + 255) / 256, 256, 0, stream>>>(row_off, col, hxb, bmu, bls, noise, out, N);
}

// Round 8
// 449.981 us; speedup vs baseline: 2.5886x; 1.0697x over previous
//
#include <hip/hip_runtime.h>
#include <hip/hip_bf16.h>
#include <math.h>

typedef __attribute__((ext_vector_type(8))) short short8;
typedef __attribute__((ext_vector_type(4))) float f32x4;

// fp32 -> bf16 round-to-nearest-even (scalar)
__device__ __forceinline__ unsigned short f2bf(float f) {
    unsigned int u = __float_as_uint(f);
    u += 0x7FFF + ((u >> 16) & 1);
    return (unsigned short)(u >> 16);
}
__device__ __forceinline__ float b2f(unsigned short s) {
    return __uint_as_float(((unsigned int)s) << 16);
}
// packed fp32x2 -> bf16x2 RNE (v_cvt_pk_bf16_f32 on gfx950)
__device__ __forceinline__ unsigned int f2bf2(float a, float b) {
    __hip_bfloat162 h = __float22bfloat162_rn(make_float2(a, b));
    return *(unsigned int*)&h;
}
// async global->LDS, 16B per lane (global_load_lds_dwordx4)
__device__ __forceinline__ void gl_lds16(const void* g, void* l) {
    __builtin_amdgcn_global_load_lds(
        (const __attribute__((address_space(1))) void*)g,
        (__attribute__((address_space(3))) void*)l, 16, 0, 0);
}

// CSR build via LDS two-level bucket sort, ZERO global atomics.
// COARSE buckets: 128 buckets x 1024 nodes (covers N<=131072).
#define EB 8192        // edges per partition block
#define BSH 10         // node >> 10 = bucket
#define NBKT 128

__global__ __launch_bounds__(256)
void k1_hist(const int* __restrict__ src, const int* __restrict__ dst,
             int* __restrict__ bhist, int E) {
    __shared__ int hist[256];
    int t = threadIdx.x;
    hist[t] = 0;
    __syncthreads();
    int base = blockIdx.x * EB;
    int end = min(base + EB, E);
    for (int e = base + 4 * t; e < end; e += 1024) {
        if (e + 3 < end) {
            int4 d4 = *(const int4*)&dst[e];
            int4 s4 = *(const int4*)&src[e];
            atomicAdd(&hist[d4.x >> BSH], 1);
            atomicAdd(&hist[d4.y >> BSH], 1);
            atomicAdd(&hist[d4.z >> BSH], 1);
            atomicAdd(&hist[d4.w >> BSH], 1);
            atomicAdd(&hist[128 + (s4.x >> BSH)], 1);
            atomicAdd(&hist[128 + (s4.y >> BSH)], 1);
            atomicAdd(&hist[128 + (s4.z >> BSH)], 1);
            atomicAdd(&hist[128 + (s4.w >> BSH)], 1);
        } else {
            for (int q = e; q < end; ++q) {
                atomicAdd(&hist[dst[q] >> BSH], 1);
                atomicAdd(&hist[128 + (src[q] >> BSH)], 1);
            }
        }
    }
    __syncthreads();
    bhist[(size_t)blockIdx.x * 256 + t] = hist[t];
}

__global__ __launch_bounds__(256)
void kc1_totals(const int* __restrict__ bhist, int* __restrict__ totals, int PB) {
    int t = threadIdx.x;
    int slice = (PB + 7) / 8;
    int b0 = blockIdx.x * slice;
    int b1 = min(b0 + slice, PB);
    int s = 0;
    for (int blk = b0; blk < b1; ++blk) s += bhist[(size_t)blk * 256 + t];
    if (s) atomicAdd(&totals[t], s);
}

__global__ __launch_bounds__(256)
void kc2_scan2(const int* __restrict__ totals, int* __restrict__ bbase_d,
               int* __restrict__ bbase_s) {
    __shared__ int s[256];
    int t = threadIdx.x;
    int v = totals[t];
    s[t] = v;
    __syncthreads();
    for (int off = 1; off < 128; off <<= 1) {
        int u = ((t & 127) >= off) ? s[t - off] : 0;
        __syncthreads();
        s[t] += u;
        __syncthreads();
    }
    int excl = s[t] - v;
    if (t < 128) bbase_d[t] = excl;
    else bbase_s[t - 128] = excl;
}

__global__ __launch_bounds__(256)
void kc3_boff(const int* __restrict__ bhist, const int* __restrict__ bbase_d,
              const int* __restrict__ bbase_s, int* __restrict__ boffT, int PB) {
    __shared__ int sums[256];
    int b = blockIdx.x;  // 0..255
    int t = threadIdx.x;
    int v = (t < PB) ? bhist[(size_t)t * 256 + b] : 0;
    sums[t] = v;
    __syncthreads();
    for (int off = 1; off < 256; off <<= 1) {
        int u = (t >= off) ? sums[t - off] : 0;
        __syncthreads();
        sums[t] += u;
        __syncthreads();
    }
    int base = (b < 128) ? bbase_d[b] : bbase_s[b - 128];
    if (t < PB) boffT[(size_t)b * PB + t] = base + sums[t] - v;
}

__global__ __launch_bounds__(256)
void k2_scatter(const int* __restrict__ src, const int* __restrict__ dst,
                const int* __restrict__ boffT, int2* __restrict__ parr,
                int* __restrict__ sarr, int E, int PB) {
    __shared__ int cnt[256];
    int t = threadIdx.x;
    int blk = blockIdx.x;
    cnt[t] = boffT[(size_t)t * PB + blk];
    __syncthreads();
    int base = blk * EB;
    int end = min(base + EB, E);
    for (int e = base + 4 * t; e < end; e += 1024) {
        if (e + 3 < end) {
            int4 s4 = *(const int4*)&src[e];
            int4 d4 = *(const int4*)&dst[e];
            int p0 = atomicAdd(&cnt[d4.x >> BSH], 1); parr[p0] = make_int2(s4.x, d4.x);
            int p1 = atomicAdd(&cnt[d4.y >> BSH], 1); parr[p1] = make_int2(s4.y, d4.y);
            int p2 = atomicAdd(&cnt[d4.z >> BSH], 1); parr[p2] = make_int2(s4.z, d4.z);
            int p3 = atomicAdd(&cnt[d4.w >> BSH], 1); parr[p3] = make_int2(s4.w, d4.w);
            int q0 = atomicAdd(&cnt[128 + (s4.x >> BSH)], 1); sarr[q0] = s4.x;
            int q1 = atomicAdd(&cnt[128 + (s4.y >> BSH)], 1); sarr[q1] = s4.y;
            int q2 = atomicAdd(&cnt[128 + (s4.z >> BSH)], 1); sarr[q2] = s4.z;
            int q3 = atomicAdd(&cnt[128 + (s4.w >> BSH)], 1); sarr[q3] = s4.w;
        } else {
            for (int q = e; q < end; ++q) {
                int sv = src[q], dv = dst[q];
                int pd = atomicAdd(&cnt[dv >> BSH], 1);
                parr[pd] = make_int2(sv, dv);
                int ps = atomicAdd(&cnt[128 + (sv >> BSH)], 1);
                sarr[ps] = sv;
            }
        }
    }
}

__global__ __launch_bounds__(1024)
void k3_dst(const int2* __restrict__ parr, const int* __restrict__ totals,
            const int* __restrict__ bbase_d, int* __restrict__ row_off,
            int* __restrict__ col, int N, int E) {
    __shared__ int hist[1024], sc[1024];
    int b = blockIdx.x, t = threadIdx.x;
    if (b == 0 && t == 0) row_off[N] = E;
    int ne = totals[b];
    int ebase = bbase_d[b];
    hist[t] = 0;
    __syncthreads();
    for (int i = t; i < ne; i += 1024)
        atomicAdd(&hist[parr[ebase + i].y & 1023], 1);
    __syncthreads();
    int h = hist[t];
    sc[t] = h;
    __syncthreads();
    for (int off = 1; off < 1024; off <<= 1) {
        int u = (t >= off) ? sc[t - off] : 0;
        __syncthreads();
        sc[t] += u;
        __syncthreads();
    }
    int excl = sc[t] - h;
    int node = b * 1024 + t;
    if (node < N) row_off[node] = ebase + excl;
    hist[t] = ebase + excl;  // reuse as scatter counters
    __syncthreads();
    for (int i = t; i < ne; i += 1024) {
        int2 pr = parr[ebase + i];
        int slot = atomicAdd(&hist[pr.y & 1023], 1);
        col[slot] = pr.x;
    }
}

__global__ __launch_bounds__(1024)
void k3_src(const int* __restrict__ sarr, const int* __restrict__ totals_s,
            const int* __restrict__ bbase_s, float* __restrict__ norm, int N) {
    __shared__ int hist[1024];
    int b = blockIdx.x, t = threadIdx.x;
    int ne = totals_s[b];
    int sb = bbase_s[b];
    hist[t] = 0;
    __syncthreads();
    for (int i = t; i < ne; i += 1024)
        atomicAdd(&hist[sarr[sb + i] & 1023], 1);
    __syncthreads();
    int node = b * 1024 + t;
    if (node < N) {
        int d = hist[t];
        norm[node] = 1.0f / (float)(d > 1 ? d : 1);
    }
}

// Pre-transpose + pre-convert weights to bf16, fragment-contiguous.
__global__ __launch_bounds__(256)
void k_wprep(const float* __restrict__ Wsh, const float* __restrict__ Wmu,
             const float* __restrict__ Wls, unsigned short* __restrict__ W1T,
             unsigned short* __restrict__ W2T) {
    int b = blockIdx.x, t = threadIdx.x;
    if (b < 128) {
        W1T[(size_t)b * 256 + t] = f2bf(Wsh[(size_t)t * 128 + b]);
    } else {
        int n = b - 128;
        if (t < 128) {
            float v = (n < 64) ? Wmu[(size_t)t * 64 + n]
                               : Wls[(size_t)t * 64 + (n - 64)];
            W2T[(size_t)n * 128 + t] = f2bf(v);
        }
    }
}

// GEMM1: outb[M,128](bf16) = (feat[M,256] fp32 @ W) * norm
// A-tile (64x256 fp32 = 64KB) staged async via global_load_lds (one vmcnt
// drain per block, full-BW streaming) into LDS with +16B/row pad (stride
// 1040B: even bank spread for ds_read_b128). R7's direct-from-global version
// was load-latency-serialized (VALUBusy 7%, 0.9 TB/s).
__global__ __launch_bounds__(256)
void k_gemm1(const float* __restrict__ A, int M,
             const unsigned short* __restrict__ W1T,
             const float* __restrict__ norm, unsigned short* __restrict__ outb) {
    __shared__ char ldsA[64 * 1040];
    const int w = threadIdx.x >> 6;
    const int lane = threadIdx.x & 63;
    const int quad = lane >> 4;
    const int l16 = lane & 15;
    const int cl = w * 16 + l16;
    const int r0 = blockIdx.x * 64;

    // stage: wave w loads rows w*16..w*16+15 (1 row = 1024B = one wave-op)
#pragma unroll
    for (int i = 0; i < 16; ++i) {
        int row = r0 + w * 16 + i;
        if (row >= M) row = M - 1;
        const char* g = (const char*)A + (size_t)row * 1024 + lane * 16;
        char* l = ldsA + (w * 16 + i) * 1040 + lane * 16;
        gl_lds16(g, l);
    }

    // W fragments (L2-resident, overlap with staging)
    short8 bw[2][8];
#pragma unroll
    for (int hf = 0; hf < 2; ++hf) {
        const unsigned short* wp = W1T + (size_t)(hf * 64 + cl) * 256 + quad * 8;
#pragma unroll
        for (int ks = 0; ks < 8; ++ks)
            bw[hf][ks] = *(const short8*)(wp + ks * 32);
    }
    __syncthreads();  // drains vmcnt(0): staging + frag loads complete

    f32x4 acc[4][2];
#pragma unroll
    for (int m = 0; m < 4; ++m) {
        acc[m][0] = (f32x4){0.f, 0.f, 0.f, 0.f};
        acc[m][1] = (f32x4){0.f, 0.f, 0.f, 0.f};
    }
#pragma unroll
    for (int ks = 0; ks < 8; ++ks) {
#pragma unroll
        for (int m = 0; m < 4; ++m) {
            const float* pr = (const float*)(ldsA + (m * 16 + l16) * 1040 +
                                             (ks * 32 + quad * 8) * 4);
            float4 x = *(const float4*)pr;
            float4 y = *(const float4*)(pr + 4);
            union { short8 v; unsigned int u[4]; } c;
            c.u[0] = f2bf2(x.x, x.y);
            c.u[1] = f2bf2(x.z, x.w);
            c.u[2] = f2bf2(y.x, y.y);
            c.u[3] = f2bf2(y.z, y.w);
            acc[m][0] = __builtin_amdgcn_mfma_f32_16x16x32_bf16(bw[0][ks], c.v, acc[m][0], 0, 0, 0);
            acc[m][1] = __builtin_amdgcn_mfma_f32_16x16x32_bf16(bw[1][ks], c.v, acc[m][1], 0, 0, 0);
        }
    }
    const int colbase = w * 16 + quad * 4;
#pragma unroll
    for (int m = 0; m < 4; ++m) {
        int row = r0 + m * 16 + l16;
        if (row < M) {
            float nm = norm[row];
            ushort4 o0, o1;
            o0.x = f2bf(acc[m][0][0] * nm); o0.y = f2bf(acc[m][0][1] * nm);
            o0.z = f2bf(acc[m][0][2] * nm); o0.w = f2bf(acc[m][0][3] * nm);
            o1.x = f2bf(acc[m][1][0] * nm); o1.y = f2bf(acc[m][1][1] * nm);
            o1.z = f2bf(acc[m][1][2] * nm); o1.w = f2bf(acc[m][1][3] * nm);
            *(ushort4*)&outb[(size_t)row * 128 + colbase] = o0;
            *(ushort4*)&outb[(size_t)row * 128 + 64 + colbase] = o1;
        }
    }
}

// GEMM2: outb[M,128](bf16) = (h[M,128](bf16) @ [Wmu|Wls]) * norm.
// A-tile 64x128 bf16 = 16KB staged in 4-row (1024B) chunks, +16B pad/chunk.
__global__ __launch_bounds__(256)
void k_gemm2(const unsigned short* __restrict__ A, int M,
             const unsigned short* __restrict__ W2T,
             const float* __restrict__ norm, unsigned short* __restrict__ outb) {
    __shared__ char ldsB[16 * 1040];
    const int w = threadIdx.x >> 6;
    const int lane = threadIdx.x & 63;
    const int quad = lane >> 4;
    const int l16 = lane & 15;
    const int cl = w * 16 + l16;
    const int r0 = blockIdx.x * 64;

#pragma unroll
    for (int i = 0; i < 4; ++i) {
        int c = w * 4 + i;          // chunk 0..15 (4 rows each)
        int crow = r0 + c * 4;
        if (crow + 4 > M) crow = M - 4;  // M multiple of 4
        const char* g = (const char*)A + (size_t)crow * 256 + lane * 16;
        char* l = ldsB + c * 1040 + lane * 16;
        gl_lds16(g, l);
    }

    short8 bw[2][4];
#pragma unroll
    for (int hf = 0; hf < 2; ++hf) {
        const unsigned short* wp = W2T + (size_t)(hf * 64 + cl) * 128 + quad * 8;
#pragma unroll
        for (int ks = 0; ks < 4; ++ks)
            bw[hf][ks] = *(const short8*)(wp + ks * 32);
    }
    __syncthreads();

    f32x4 acc[4][2];
#pragma unroll
    for (int m = 0; m < 4; ++m) {
        acc[m][0] = (f32x4){0.f, 0.f, 0.f, 0.f};
        acc[m][1] = (f32x4){0.f, 0.f, 0.f, 0.f};
    }
#pragma unroll
    for (int ks = 0; ks < 4; ++ks) {
#pragma unroll
        for (int m = 0; m < 4; ++m) {
            int row = m * 16 + l16;
            short8 af = *(const short8*)(ldsB + (row >> 2) * 1040 + (row & 3) * 256 +
                                         (ks * 32 + quad * 8) * 2);
            acc[m][0] = __builtin_amdgcn_mfma_f32_16x16x32_bf16(bw[0][ks], af, acc[m][0], 0, 0, 0);
            acc[m][1] = __builtin_amdgcn_mfma_f32_16x16x32_bf16(bw[1][ks], af, acc[m][1], 0, 0, 0);
        }
    }
    const int colbase = w * 16 + quad * 4;
#pragma unroll
    for (int m = 0; m < 4; ++m) {
        int row = r0 + m * 16 + l16;
        if (row < M) {
            float nm = norm[row];
            ushort4 o0, o1;
            o0.x = f2bf(acc[m][0][0] * nm); o0.y = f2bf(acc[m][0][1] * nm);
            o0.z = f2bf(acc[m][0][2] * nm); o0.w = f2bf(acc[m][0][3] * nm);
            o1.x = f2bf(acc[m][1][0] * nm); o1.y = f2bf(acc[m][1][1] * nm);
            o1.z = f2bf(acc[m][1][2] * nm); o1.w = f2bf(acc[m][1][3] * nm);
            *(ushort4*)&outb[(size_t)row * 128 + colbase] = o0;
            *(ushort4*)&outb[(size_t)row * 128 + 64 + colbase] = o1;
        }
    }
}

// SpMM stage 1: half-wave (32 lanes x ushort4 = 256B bf16 row) per node.
// 8-wide unroll: 8 independent row gathers in flight.
__global__ __launch_bounds__(256)
void k_spmm_relu(const int* __restrict__ row_off, const int* __restrict__ col,
                 const unsigned short* __restrict__ hxb, const float* __restrict__ bias,
                 unsigned short* __restrict__ hb, int N) {
    int g = (blockIdx.x * blockDim.x + threadIdx.x) >> 5;
    int l = threadIdx.x & 31;
    if (g >= N) return;
    int e0 = row_off[g], e1 = row_off[g + 1];
    const ushort4* base = (const ushort4*)hxb;
    float4 acc = make_float4(0.f, 0.f, 0.f, 0.f);
    int e = e0;
    for (; e + 7 < e1; e += 8) {
        ushort4 v0 = base[(size_t)col[e] * 32 + l];
        ushort4 v1 = base[(size_t)col[e + 1] * 32 + l];
        ushort4 v2 = base[(size_t)col[e + 2] * 32 + l];
        ushort4 v3 = base[(size_t)col[e + 3] * 32 + l];
        ushort4 v4 = base[(size_t)col[e + 4] * 32 + l];
        ushort4 v5 = base[(size_t)col[e + 5] * 32 + l];
        ushort4 v6 = base[(size_t)col[e + 6] * 32 + l];
        ushort4 v7 = base[(size_t)col[e + 7] * 32 + l];
        acc.x += ((b2f(v0.x) + b2f(v1.x)) + (b2f(v2.x) + b2f(v3.x))) +
                 ((b2f(v4.x) + b2f(v5.x)) + (b2f(v6.x) + b2f(v7.x)));
        acc.y += ((b2f(v0.y) + b2f(v1.y)) + (b2f(v2.y) + b2f(v3.y))) +
                 ((b2f(v4.y) + b2f(v5.y)) + (b2f(v6.y) + b2f(v7.y)));
        acc.z += ((b2f(v0.z) + b2f(v1.z)) + (b2f(v2.z) + b2f(v3.z))) +
                 ((b2f(v4.z) + b2f(v5.z)) + (b2f(v6.z) + b2f(v7.z)));
        acc.w += ((b2f(v0.w) + b2f(v1.w)) + (b2f(v2.w) + b2f(v3.w))) +
                 ((b2f(v4.w) + b2f(v5.w)) + (b2f(v6.w) + b2f(v7.w)));
    }
    for (; e + 1 < e1; e += 2) {
        ushort4 a = base[(size_t)col[e] * 32 + l];
        ushort4 b = base[(size_t)col[e + 1] * 32 + l];
        acc.x += b2f(a.x) + b2f(b.x);
        acc.y += b2f(a.y) + b2f(b.y);
        acc.z += b2f(a.z) + b2f(b.z);
        acc.w += b2f(a.w) + b2f(b.w);
    }
    if (e < e1) {
        ushort4 a = base[(size_t)col[e] * 32 + l];
        acc.x += b2f(a.x); acc.y += b2f(a.y); acc.z += b2f(a.z); acc.w += b2f(a.w);
    }
    float4 bi = ((const float4*)bias)[l];
    ushort4 r;
    r.x = f2bf(fmaxf(acc.x + bi.x, 0.f));
    r.y = f2bf(fmaxf(acc.y + bi.y, 0.f));
    r.z = f2bf(fmaxf(acc.z + bi.z, 0.f));
    r.w = f2bf(fmaxf(acc.w + bi.w, 0.f));
    ((ushort4*)hb)[(size_t)g * 32 + l] = r;
}

// SpMM stage 2 + reparameterization. Lane l<16: mu cols 4l..4l+3; lane l+16: ls.
__global__ __launch_bounds__(256)
void k_spmm_out(const int* __restrict__ row_off, const int* __restrict__ col,
                const unsigned short* __restrict__ hcb, const float* __restrict__ bmu,
                const float* __restrict__ bls, const float* __restrict__ noise,
                float* __restrict__ out, int N) {
    int g = (blockIdx.x * blockDim.x + threadIdx.x) >> 5;
    int l = threadIdx.x & 31;
    if (g >= N) return;
    int e0 = row_off[g], e1 = row_off[g + 1];
    const ushort4* base = (const ushort4*)hcb;
    float4 acc = make_float4(0.f, 0.f, 0.f, 0.f);
    int e = e0;
    for (; e + 7 < e1; e += 8) {
        ushort4 v0 = base[(size_t)col[e] * 32 + l];
        ushort4 v1 = base[(size_t)col[e + 1] * 32 + l];
        ushort4 v2 = base[(size_t)col[e + 2] * 32 + l];
        ushort4 v3 = base[(size_t)col[e + 3] * 32 + l];
        ushort4 v4 = base[(size_t)col[e + 4] * 32 + l];
        ushort4 v5 = base[(size_t)col[e + 5] * 32 + l];
        ushort4 v6 = base[(size_t)col[e + 6] * 32 + l];
        ushort4 v7 = base[(size_t)col[e + 7] * 32 + l];
        acc.x += ((b2f(v0.x) + b2f(v1.x)) + (b2f(v2.x) + b2f(v3.x))) +
                 ((b2f(v4.x) + b2f(v5.x)) + (b2f(v6.x) + b2f(v7.x)));
        acc.y += ((b2f(v0.y) + b2f(v1.y)) + (b2f(v2.y) + b2f(v3.y))) +
                 ((b2f(v4.y) + b2f(v5.y)) + (b2f(v6.y) + b2f(v7.y)));
        acc.z += ((b2f(v0.z) + b2f(v1.z)) + (b2f(v2.z) + b2f(v3.z))) +
                 ((b2f(v4.z) + b2f(v5.z)) + (b2f(v6.z) + b2f(v7.z)));
        acc.w += ((b2f(v0.w) + b2f(v1.w)) + (b2f(v2.w) + b2f(v3.w))) +
                 ((b2f(v4.w) + b2f(v5.w)) + (b2f(v6.w) + b2f(v7.w)));
    }
    for (; e + 1 < e1; e += 2) {
        ushort4 a = base[(size_t)col[e] * 32 + l];
        ushort4 b = base[(size_t)col[e + 1] * 32 + l];
        acc.x += b2f(a.x) + b2f(b.x);
        acc.y += b2f(a.y) + b2f(b.y);
        acc.z += b2f(a.z) + b2f(b.z);
        acc.w += b2f(a.w) + b2f(b.w);
    }
    if (e < e1) {
        ushort4 a = base[(size_t)col[e] * 32 + l];
        acc.x += b2f(a.x); acc.y += b2f(a.y); acc.z += b2f(a.z); acc.w += b2f(a.w);
    }
    int lane64 = threadIdx.x & 63;
    int p = (lane64 + 16) & 63;
    float lx = __shfl(acc.x, p, 64);
    float ly = __shfl(acc.y, p, 64);
    float lz = __shfl(acc.z, p, 64);
    float lw = __shfl(acc.w, p, 64);
    if (l < 16) {
        float4 bm = ((const float4*)bmu)[l];
        float4 bl = ((const float4*)bls)[l];
        float4 nz = ((const float4*)noise)[(size_t)g * 16 + l];
        float4 o;
        o.x = (acc.x + bm.x) + nz.x * expf(lx + bl.x);
        o.y = (acc.y + bm.y) + nz.y * expf(ly + bl.y);
        o.z = (acc.z + bm.z) + nz.z * expf(lz + bl.z);
        o.w = (acc.w + bm.w) + nz.w * expf(lw + bl.w);
        ((float4*)out)[(size_t)g * 16 + l] = o;
    }
}

static inline char* align64(char* p) {
    return (char*)(((uintptr_t)p + 63) & ~(uintptr_t)63);
}

extern "C" void kernel_launch(void* const* d_in, const int* in_sizes, int n_in,
                              void* d_out, int out_size, void* d_ws, size_t ws_size,
                              hipStream_t stream) {
    const float* feat  = (const float*)d_in[0];
    const float* Wsh   = (const float*)d_in[1];
    const float* bsh   = (const float*)d_in[2];
    const float* Wmu   = (const float*)d_in[3];
    const float* bmu   = (const float*)d_in[4];
    const float* Wls   = (const float*)d_in[5];
    const float* bls   = (const float*)d_in[6];
    const float* noise = (const float*)d_in[7];
    const int*   src   = (const int*)d_in[8];
    const int*   dst   = (const int*)d_in[9];
    float* out = (float*)d_out;

    const int N = in_sizes[0] / 256;   // 100000 (<=131072 for 128 coarse buckets)
    const int E = in_sizes[8];         // 1600000
    const int PB = (E + EB - 1) / EB;  // 196

    char* p = (char*)d_ws;
    float* norm   = (float*)p;                  p += (size_t)N * 4;         p = align64(p);
    int* row_off  = (int*)p;                    p += (size_t)(N + 4) * 4;   p = align64(p);
    int* totals   = (int*)p;                    p += 256 * 4;
    int* bbase_d  = (int*)p;                    p += 128 * 4;
    int* bbase_s  = (int*)p;                    p += 128 * 4;               p = align64(p);
    unsigned short* W1T = (unsigned short*)p;   p += (size_t)128 * 256 * 2; // 64 KB
    unsigned short* W2T = (unsigned short*)p;   p += (size_t)128 * 128 * 2; // 32 KB
    p = align64(p);
    int* bhist    = (int*)p;                    p += (size_t)PB * 256 * 4;  p = align64(p);
    int* boffT    = (int*)p;                    p += (size_t)256 * PB * 4;  p = align64(p);
    int2* parr    = (int2*)p;                   p += (size_t)E * 8;
    int* sarr     = (int*)p;                    p += (size_t)E * 4;
    int* col      = (int*)p;                    p += (size_t)E * 4;         p = align64(p);
    unsigned short* hxb = (unsigned short*)p;                  // N*128 bf16 (hx, then hc)
    unsigned short* hb  = (unsigned short*)d_out;              // N*128 bf16 scratch

    // ---- CSR build (no global atomics except 256 tiny totals adds) ----
    hipMemsetAsync(totals, 0, 256 * sizeof(int), stream);
    k_wprep<<<256, 256, 0, stream>>>(Wsh, Wmu, Wls, W1T, W2T);
    k1_hist<<<PB, 256, 0, stream>>>(src, dst, bhist, E);
    kc1_totals<<<8, 256, 0, stream>>>(bhist, totals, PB);
    kc2_scan2<<<1, 256, 0, stream>>>(totals, bbase_d, bbase_s);
    kc3_boff<<<256, 256, 0, stream>>>(bhist, bbase_d, bbase_s, boffT, PB);
    k2_scatter<<<PB, 256, 0, stream>>>(src, dst, boffT, parr, sarr, E, PB);
    k3_dst<<<NBKT, 1024, 0, stream>>>(parr, totals, bbase_d, row_off, col, N, E);
    k3_src<<<NBKT, 1024, 0, stream>>>(sarr, totals + 128, bbase_s, norm, N);

    // ---- dense pipeline ----
    int gtiles = (N + 63) / 64;  // 1563
    k_gemm1<<<gtiles, 256, 0, stream>>>(feat, N, W1T, norm, hxb);
    k_spmm_relu<<<(N * 32 + 255) / 256, 256, 0, stream>>>(row_off, col, hxb, bsh, hb, N);
    k_gemm2<<<gtiles, 256, 0, stream>>>(hb, N, W2T, norm, hxb);
    k_spmm_out<<<(N * 32 + 255) / 256, 256, 0, stream>>>(row_off, col, hxb, bmu, bls, noise, out, N);
}